// Round 4
// 1929.181 us; speedup vs baseline: 1.0262x; 1.0262x over previous
//
#include <hip/hip_runtime.h>

#define FH 128
#define NEG 0.01f
#define BNEPS 1e-5f

typedef unsigned int uint32;
typedef unsigned short u16;
typedef __attribute__((ext_vector_type(8))) short bf16x8;
typedef __attribute__((ext_vector_type(4))) float f32x4;

__device__ __forceinline__ float lrelu(float v){ return v >= 0.f ? v : NEG * v; }
__device__ __forceinline__ float bfl(uint32 u){ return __uint_as_float(u << 16); }
__device__ __forceinline__ float bfh(uint32 u){ return __uint_as_float(u & 0xffff0000u); }
__device__ __forceinline__ u16 f2bf(float f){
  uint32 u = __float_as_uint(f);
  u += 0x7fffu + ((u >> 16) & 1u);   // RNE
  return (u16)(u >> 16);
}

// ---------------- fp32 -> bf16 table conversion ----------------
__global__ void k_cvt(const float* __restrict__ x, u16* __restrict__ t, int n4){
  int g = blockIdx.x * 256 + threadIdx.x;
  int stride = gridDim.x * 256;
  for (int i = g; i < n4; i += stride){
    float4 v = ((const float4*)x)[i];
    ushort4 p;
    p.x = f2bf(v.x); p.y = f2bf(v.y); p.z = f2bf(v.z); p.w = f2bf(v.w);
    ((ushort4*)t)[i] = p;
  }
}

// ---------------- CSR build ----------------
__global__ void k_hist(const int* __restrict__ dst, int E, int* __restrict__ cnt){
  int i = blockIdx.x * 256 + threadIdx.x;
  if (i < E) atomicAdd(&cnt[dst[i]], 1);
}

__global__ void k_fill(const int* __restrict__ src, const int* __restrict__ dst, int E,
                       int* __restrict__ cur, int* __restrict__ csr){
  int i = blockIdx.x * 256 + threadIdx.x;
  if (i < E){
    int slot = atomicAdd(&cur[dst[i]], 1);
    csr[slot] = src[i];
  }
}

__global__ void k_chunk_sums(const int* c0, const int* c1, const int* c2, const int* c3,
                             int l0, int l1, int l2, int l3, int* __restrict__ sums){
  int a = blockIdx.y;
  const int* c = a==0?c0 : a==1?c1 : a==2?c2 : c3;
  int len     = a==0?l0 : a==1?l1 : a==2?l2 : l3;
  int base = blockIdx.x * 1024;
  if (base >= len) return;
  int t = threadIdx.x;
  int s = 0;
  #pragma unroll
  for (int u = 0; u < 4; ++u){ int i = base + t*4 + u; if (i < len) s += c[i]; }
  __shared__ int red[256];
  red[t] = s; __syncthreads();
  for (int o = 128; o > 0; o >>= 1){ if (t < o) red[t] += red[t+o]; __syncthreads(); }
  if (t == 0) sums[a*256 + blockIdx.x] = red[0];
}

__global__ void k_scan_sums(int* sums, int n0, int n1, int n2, int n3){
  int a = blockIdx.x;
  int n = a==0?n0 : a==1?n1 : a==2?n2 : n3;
  int t = threadIdx.x;
  __shared__ int shm[256];
  shm[t] = (t < n) ? sums[a*256 + t] : 0;
  __syncthreads();
  for (int o = 1; o < 256; o <<= 1){
    int x = shm[t];
    if (t >= o) x += shm[t-o];
    __syncthreads();
    shm[t] = x;
    __syncthreads();
  }
  sums[a*256 + t] = t ? shm[t-1] : 0;
}

__global__ void k_write_offsets(const int* c0, const int* c1, const int* c2, const int* c3,
                                int* o0, int* o1, int* o2, int* o3,
                                int* u0, int* u1, int* u2, int* u3,
                                int l0, int l1, int l2, int l3,
                                const int* __restrict__ sums){
  int a = blockIdx.y;
  const int* c = a==0?c0 : a==1?c1 : a==2?c2 : c3;
  int* off     = a==0?o0 : a==1?o1 : a==2?o2 : o3;
  int* cur     = a==0?u0 : a==1?u1 : a==2?u2 : u3;
  int len      = a==0?l0 : a==1?l1 : a==2?l2 : l3;
  int base = blockIdx.x * 1024;
  if (base >= len) return;
  int t = threadIdx.x;
  int v[4]; int s = 0;
  #pragma unroll
  for (int u = 0; u < 4; ++u){ int i = base + t*4 + u; v[u] = (i < len) ? c[i] : 0; s += v[u]; }
  __shared__ int shm[256];
  shm[t] = s; __syncthreads();
  for (int o = 1; o < 256; o <<= 1){
    int x = shm[t];
    if (t >= o) x += shm[t-o];
    __syncthreads();
    shm[t] = x;
    __syncthreads();
  }
  int run = (t ? shm[t-1] : 0) + sums[a*256 + blockIdx.x];
  #pragma unroll
  for (int u = 0; u < 4; ++u){
    int i = base + t*4 + u;
    if (i < len){
      off[i] = run; cur[i] = run; run += v[u];
      if (i == len - 1) off[len] = run;
    }
  }
}

// ---------------- weight concat (bf16, transposed: Wt[which][c][k]) ----------------
__global__ void k_prep(const float* __restrict__ Wl, const float* __restrict__ bl,
                       const float* __restrict__ Wr, u16* __restrict__ wt,
                       float* __restrict__ bcat){
  int g = blockIdx.x * 256 + threadIdx.x;
  const int NW = 4 * 128 * 384;
  if (g < NW){
    int which = g / 49152;          // blk*2 + side
    int blk = which >> 1, side = which & 1;
    int idx = g % 49152;
    int c = idx / 384;              // out col 0..127
    int k = idx % 384;              // 0..383
    int part = k >> 7, kk = k & 127;
    int tA = side == 0 ? 0 : 1;
    int tB = side == 0 ? 2 : 3;
    float v;
    if (part == 0)      v = 0.5f * Wl[(((blk*4 + tA)*128 + c)*128) + kk];
    else if (part == 1) v = 0.5f * Wl[(((blk*4 + tB)*128 + c)*128) + kk];
    else v = 0.5f * (Wr[(((blk*4 + tA)*128 + c)*128) + kk] + Wr[(((blk*4 + tB)*128 + c)*128) + kk]);
    wt[g] = f2bf(v);
  } else if (g < NW + 512){
    int i = g - NW;
    int which = i >> 7;
    int blk = which >> 1, side = which & 1;
    int c = i & 127;
    int tA = side == 0 ? 0 : 1;
    int tB = side == 0 ? 2 : 3;
    bcat[which*128 + c] = 0.5f * (bl[(blk*4 + tA)*128 + c] + bl[(blk*4 + tB)*128 + c]);
  }
}

// ---------------- fused gather-mean + MFMA GEMM ----------------
// 32 rows x 128 cols per block; A staged as bf16 in LDS (one barrier), matmul
// via mfma_f32_16x16x32_bf16 with B read straight from L2-resident Wt[c][k].
// Gather inner loop: unroll 8 (8 independent loads in flight per wave, was 4).
// Summation order identical to the unroll-4 version (vx: even edges, ux: odd).
__global__ __launch_bounds__(256, 6) void k_gemm(
    int M,
    const int* __restrict__ off0, const int* __restrict__ csr0, const u16* __restrict__ tab0,
    const float* __restrict__ sc0, const float* __restrict__ sh0,
    const int* __restrict__ off1, const int* __restrict__ csr1, const u16* __restrict__ tab1,
    const float* __restrict__ sc1, const float* __restrict__ sh1,
    const u16* __restrict__ tabd, const float* __restrict__ scd, const float* __restrict__ shd,
    const u16* __restrict__ Wt, const float* __restrict__ bias,
    float* __restrict__ out32, u16* __restrict__ out16)
{
  __shared__ u16 As[32][392];     // 392 = 384 + 8 pad -> 16B-unit stride 49 (odd): 2-way max
  const int tid = threadIdx.x;
  const int row0 = blockIdx.x * 32;
  const int lane = tid & 63;
  const int wave = tid >> 6;

  // ---- stage A = [mean_gather(p0) | mean_gather(p1) | self(p2)] as bf16 ----
  for (int part = 0; part < 3; ++part){
    const int* off; const int* csr; const u16* tab; const float* sc; const float* sh;
    if (part == 0){ off = off0; csr = csr0; tab = tab0; sc = sc0; sh = sh0; }
    else if (part == 1){ off = off1; csr = csr1; tab = tab1; sc = sc1; sh = sh1; }
    else { off = nullptr; csr = nullptr; tab = tabd; sc = scd; sh = shd; }
    const bool bn = (sc != nullptr);
    float scx = 1.f, scy = 1.f, shx = 0.f, shy = 0.f;
    if (bn){
      scx = sc[2*lane]; scy = sc[2*lane+1];
      shx = sh[2*lane]; shy = sh[2*lane+1];
    }

    for (int rr = 0; rr < 8; ++rr){
      int r = (wave << 3) + rr;
      int row = row0 + r;                 // wave-uniform
      float vx = 0.f, vy = 0.f;
      if (row < M){
        if (part < 2){
          int s = off[row], e = off[row+1];
          int n = e - s;
          float ux = 0.f, uy = 0.f;
          for (int base = s; base < e; base += 64){
            int rem = e - base; if (rem > 64) rem = 64;
            int vidx = 0;
            if (base + lane < e) vidx = csr[base + lane];   // all indices in 1 load
            int i = 0;
            if (bn){
              for (; i + 8 <= rem; i += 8){
                int t0 = __shfl(vidx, i),   t1 = __shfl(vidx, i+1);
                int t2 = __shfl(vidx, i+2), t3 = __shfl(vidx, i+3);
                int t4 = __shfl(vidx, i+4), t5 = __shfl(vidx, i+5);
                int t6 = __shfl(vidx, i+6), t7 = __shfl(vidx, i+7);
                uint32 x0 = *(const uint32*)(tab + (size_t)t0*FH + 2*lane);
                uint32 x1 = *(const uint32*)(tab + (size_t)t1*FH + 2*lane);
                uint32 x2 = *(const uint32*)(tab + (size_t)t2*FH + 2*lane);
                uint32 x3 = *(const uint32*)(tab + (size_t)t3*FH + 2*lane);
                uint32 x4 = *(const uint32*)(tab + (size_t)t4*FH + 2*lane);
                uint32 x5 = *(const uint32*)(tab + (size_t)t5*FH + 2*lane);
                uint32 x6 = *(const uint32*)(tab + (size_t)t6*FH + 2*lane);
                uint32 x7 = *(const uint32*)(tab + (size_t)t7*FH + 2*lane);
                vx += lrelu(fmaf(bfl(x0), scx, shx)); vy += lrelu(fmaf(bfh(x0), scy, shy));
                ux += lrelu(fmaf(bfl(x1), scx, shx)); uy += lrelu(fmaf(bfh(x1), scy, shy));
                vx += lrelu(fmaf(bfl(x2), scx, shx)); vy += lrelu(fmaf(bfh(x2), scy, shy));
                ux += lrelu(fmaf(bfl(x3), scx, shx)); uy += lrelu(fmaf(bfh(x3), scy, shy));
                vx += lrelu(fmaf(bfl(x4), scx, shx)); vy += lrelu(fmaf(bfh(x4), scy, shy));
                ux += lrelu(fmaf(bfl(x5), scx, shx)); uy += lrelu(fmaf(bfh(x5), scy, shy));
                vx += lrelu(fmaf(bfl(x6), scx, shx)); vy += lrelu(fmaf(bfh(x6), scy, shy));
                ux += lrelu(fmaf(bfl(x7), scx, shx)); uy += lrelu(fmaf(bfh(x7), scy, shy));
              }
              for (; i + 4 <= rem; i += 4){
                int s0 = __shfl(vidx, i),   s1 = __shfl(vidx, i+1);
                int s2 = __shfl(vidx, i+2), s3 = __shfl(vidx, i+3);
                uint32 x0 = *(const uint32*)(tab + (size_t)s0*FH + 2*lane);
                uint32 x1 = *(const uint32*)(tab + (size_t)s1*FH + 2*lane);
                uint32 x2 = *(const uint32*)(tab + (size_t)s2*FH + 2*lane);
                uint32 x3 = *(const uint32*)(tab + (size_t)s3*FH + 2*lane);
                vx += lrelu(fmaf(bfl(x0), scx, shx)); vy += lrelu(fmaf(bfh(x0), scy, shy));
                ux += lrelu(fmaf(bfl(x1), scx, shx)); uy += lrelu(fmaf(bfh(x1), scy, shy));
                vx += lrelu(fmaf(bfl(x2), scx, shx)); vy += lrelu(fmaf(bfh(x2), scy, shy));
                ux += lrelu(fmaf(bfl(x3), scx, shx)); uy += lrelu(fmaf(bfh(x3), scy, shy));
              }
              for (; i < rem; ++i){
                int s0 = __shfl(vidx, i);
                uint32 x0 = *(const uint32*)(tab + (size_t)s0*FH + 2*lane);
                vx += lrelu(fmaf(bfl(x0), scx, shx)); vy += lrelu(fmaf(bfh(x0), scy, shy));
              }
            } else {
              for (; i + 8 <= rem; i += 8){
                int t0 = __shfl(vidx, i),   t1 = __shfl(vidx, i+1);
                int t2 = __shfl(vidx, i+2), t3 = __shfl(vidx, i+3);
                int t4 = __shfl(vidx, i+4), t5 = __shfl(vidx, i+5);
                int t6 = __shfl(vidx, i+6), t7 = __shfl(vidx, i+7);
                uint32 x0 = *(const uint32*)(tab + (size_t)t0*FH + 2*lane);
                uint32 x1 = *(const uint32*)(tab + (size_t)t1*FH + 2*lane);
                uint32 x2 = *(const uint32*)(tab + (size_t)t2*FH + 2*lane);
                uint32 x3 = *(const uint32*)(tab + (size_t)t3*FH + 2*lane);
                uint32 x4 = *(const uint32*)(tab + (size_t)t4*FH + 2*lane);
                uint32 x5 = *(const uint32*)(tab + (size_t)t5*FH + 2*lane);
                uint32 x6 = *(const uint32*)(tab + (size_t)t6*FH + 2*lane);
                uint32 x7 = *(const uint32*)(tab + (size_t)t7*FH + 2*lane);
                vx += bfl(x0); vy += bfh(x0);
                ux += bfl(x1); uy += bfh(x1);
                vx += bfl(x2); vy += bfh(x2);
                ux += bfl(x3); uy += bfh(x3);
                vx += bfl(x4); vy += bfh(x4);
                ux += bfl(x5); uy += bfh(x5);
                vx += bfl(x6); vy += bfh(x6);
                ux += bfl(x7); uy += bfh(x7);
              }
              for (; i + 4 <= rem; i += 4){
                int s0 = __shfl(vidx, i),   s1 = __shfl(vidx, i+1);
                int s2 = __shfl(vidx, i+2), s3 = __shfl(vidx, i+3);
                uint32 x0 = *(const uint32*)(tab + (size_t)s0*FH + 2*lane);
                uint32 x1 = *(const uint32*)(tab + (size_t)s1*FH + 2*lane);
                uint32 x2 = *(const uint32*)(tab + (size_t)s2*FH + 2*lane);
                uint32 x3 = *(const uint32*)(tab + (size_t)s3*FH + 2*lane);
                vx += bfl(x0); vy += bfh(x0);
                ux += bfl(x1); uy += bfh(x1);
                vx += bfl(x2); vy += bfh(x2);
                ux += bfl(x3); uy += bfh(x3);
              }
              for (; i < rem; ++i){
                int s0 = __shfl(vidx, i);
                uint32 x0 = *(const uint32*)(tab + (size_t)s0*FH + 2*lane);
                vx += bfl(x0); vy += bfh(x0);
              }
            }
          }
          float inv = 1.f / (float)(n > 1 ? n : 1);
          vx = (vx + ux) * inv;
          vy = (vy + uy) * inv;
        } else {
          uint32 x = *(const uint32*)(tabd + (size_t)row*FH + 2*lane);
          float fx = bfl(x), fy = bfh(x);
          if (bn){
            vx = lrelu(fmaf(fx, scx, shx));
            vy = lrelu(fmaf(fy, scy, shy));
          } else { vx = fx; vy = fy; }
        }
      }
      uint32 pk = ((uint32)f2bf(vy) << 16) | (uint32)f2bf(vx);
      *(uint32*)&As[r][part*128 + 2*lane] = pk;
    }
  }
  __syncthreads();

  // ---- MFMA: wave = 16 rows x 64 cols; K = 384 ----
  const int rowtile = wave >> 1;      // 0..1
  const int colhalf = wave & 1;       // 0..1
  const int qm  = lane & 15;
  const int quad = lane >> 4;
  f32x4 acc[4] = {{0,0,0,0},{0,0,0,0},{0,0,0,0},{0,0,0,0}};
  const u16* abase = &As[rowtile*16 + qm][quad*8];
  const u16* wbase = Wt + ((size_t)(colhalf*64 + qm) * 384 + quad*8);

  #pragma unroll
  for (int k0 = 0; k0 < 384; k0 += 32){
    bf16x8 a  = *(const bf16x8*)(abase + k0);
    bf16x8 b0 = *(const bf16x8*)(wbase + 0*16*384 + k0);
    bf16x8 b1 = *(const bf16x8*)(wbase + 1*16*384 + k0);
    bf16x8 b2 = *(const bf16x8*)(wbase + 2*16*384 + k0);
    bf16x8 b3 = *(const bf16x8*)(wbase + 3*16*384 + k0);
    acc[0] = __builtin_amdgcn_mfma_f32_16x16x32_bf16(a, b0, acc[0], 0, 0, 0);
    acc[1] = __builtin_amdgcn_mfma_f32_16x16x32_bf16(a, b1, acc[1], 0, 0, 0);
    acc[2] = __builtin_amdgcn_mfma_f32_16x16x32_bf16(a, b2, acc[2], 0, 0, 0);
    acc[3] = __builtin_amdgcn_mfma_f32_16x16x32_bf16(a, b3, acc[3], 0, 0, 0);
  }

  // ---- epilogue: D[m=quad*4+reg][n=qm] ----
  #pragma unroll
  for (int f = 0; f < 4; ++f){
    int col = colhalf*64 + f*16 + qm;
    float bi = bias[col];
    #pragma unroll
    for (int reg = 0; reg < 4; ++reg){
      int row = row0 + rowtile*16 + quad*4 + reg;
      if (row < M){
        float o = acc[f][reg] + bi;
        if (out32) out32[(size_t)row*FH + col] = o;
        if (out16) out16[(size_t)row*FH + col] = f2bf(o);
      }
    }
  }
}

// ---------------- BN ----------------
__global__ void k_bn_stats(const float* __restrict__ x, int M,
                           float* __restrict__ gsum, float* __restrict__ gsq){
  int t = threadIdx.x;
  int f = t & 127;
  int half = t >> 7;
  float s = 0.f, q = 0.f;
  for (int row = blockIdx.x*2 + half; row < M; row += gridDim.x*2){
    float v = x[(size_t)row*FH + f];
    s += v; q += v*v;
  }
  __shared__ float red[256];
  red[t] = s; __syncthreads();
  if (t < 128) atomicAdd(&gsum[t], red[t] + red[t+128]);
  __syncthreads();
  red[t] = q; __syncthreads();
  if (t < 128) atomicAdd(&gsq[t], red[t] + red[t+128]);
}

__global__ void k_bn_stats16(const u16* __restrict__ x, int M,
                             float* __restrict__ gsum, float* __restrict__ gsq){
  int t = threadIdx.x;
  int f = t & 127;
  int half = t >> 7;
  float s = 0.f, q = 0.f;
  for (int row = blockIdx.x*2 + half; row < M; row += gridDim.x*2){
    float v = __uint_as_float(((uint32)x[(size_t)row*FH + f]) << 16);
    s += v; q += v*v;
  }
  __shared__ float red[256];
  red[t] = s; __syncthreads();
  if (t < 128) atomicAdd(&gsum[t], red[t] + red[t+128]);
  __syncthreads();
  red[t] = q; __syncthreads();
  if (t < 128) atomicAdd(&gsq[t], red[t] + red[t+128]);
}

__global__ void k_bn_finalize(const float* __restrict__ sF, const float* __restrict__ qF, float invMF,
                              const float* __restrict__ sH, const float* __restrict__ qH, float invMH,
                              const float* __restrict__ gamma, const float* __restrict__ beta,
                              float* scF, float* shF, float* scH, float* shH){
  int t = threadIdx.x;
  if (t < 128){
    float mu = sF[t] * invMF;
    float var = qF[t] * invMF - mu*mu;
    float s = gamma[t] * rsqrtf(var + BNEPS);
    scF[t] = s; shF[t] = beta[t] - mu*s;
  } else {
    int f = t - 128;
    float mu = sH[f] * invMH;
    float var = qH[f] * invMH - mu*mu;
    float s = gamma[f] * rsqrtf(var + BNEPS);
    scH[f] = s; shH[f] = beta[f] - mu*s;
  }
}

__global__ void k_apply(float* __restrict__ x, int n4,
                        const float* __restrict__ sc, const float* __restrict__ shf){
  int g = blockIdx.x * blockDim.x + threadIdx.x;
  int stride = gridDim.x * blockDim.x;
  for (int i = g; i < n4; i += stride){
    float4 v = ((const float4*)x)[i];
    int f = (i*4) & 127;
    float4 s = *(const float4*)(sc + f);
    float4 b = *(const float4*)(shf + f);
    v.x = lrelu(fmaf(v.x, s.x, b.x));
    v.y = lrelu(fmaf(v.y, s.y, b.y));
    v.z = lrelu(fmaf(v.z, s.z, b.z));
    v.w = lrelu(fmaf(v.w, s.w, b.w));
    ((float4*)x)[i] = v;
  }
}

// ---------------- launch ----------------
extern "C" void kernel_launch(void* const* d_in, const int* in_sizes, int n_in,
                              void* d_out, int out_size, void* d_ws, size_t ws_size,
                              hipStream_t stream) {
  const float* x_host = (const float*)d_in[0];
  const float* x_flow = (const float*)d_in[1];
  const int* ei_s  = (const int*)d_in[2];
  const int* ei_rv = (const int*)d_in[3];
  const int* ei_p  = (const int*)d_in[4];
  const int* ei_rc = (const int*)d_in[5];
  const float* Wl    = (const float*)d_in[6];
  const float* bl    = (const float*)d_in[7];
  const float* Wr    = (const float*)d_in[8];
  const float* gamma = (const float*)d_in[9];
  const float* beta  = (const float*)d_in[10];

  const int NH = in_sizes[0] / FH;   // 50000
  const int NF = in_sizes[1] / FH;   // 200000
  const int Es  = in_sizes[2] / 2;
  const int Erv = in_sizes[3] / 2;
  const int Ep  = in_sizes[4] / 2;
  const int Erc = in_sizes[5] / 2;

  float* out_h = (float*)d_out;
  float* out_f = (float*)d_out + (size_t)NH * FH;

  char* p = (char*)d_ws;
  auto alloc = [&](size_t bytes) -> void* {
    void* r = (void*)p;
    p += (bytes + 255) & ~(size_t)255;
    return r;
  };
  u16* xf16  = (u16*)alloc((size_t)NF * FH * 2);  // bf16 input tables
  u16* xh16  = (u16*)alloc((size_t)NH * FH * 2);
  u16* f16_0 = (u16*)alloc((size_t)NF * FH * 2);  // block-0 raw outputs (bf16)
  u16* h16_0 = (u16*)alloc((size_t)NH * FH * 2);
  u16* wcat  = (u16*)alloc((size_t)4 * 49152 * 2); // bf16 Wt[which][c][k]
  float* bcat   = (float*)alloc(512 * 4);
  float* stats  = (float*)alloc(1024 * 4);
  float* ssbuf  = (float*)alloc(1024 * 4);
  int* cnt_s = (int*)alloc((size_t)NF * 4);
  int* cnt_p = (int*)alloc((size_t)NF * 4);
  int* cnt_r = (int*)alloc((size_t)NH * 4);
  int* cnt_q = (int*)alloc((size_t)NH * 4);
  int* off_s = (int*)alloc((size_t)(NF+1) * 4);
  int* off_p = (int*)alloc((size_t)(NF+1) * 4);
  int* off_r = (int*)alloc((size_t)(NH+1) * 4);
  int* off_q = (int*)alloc((size_t)(NH+1) * 4);
  int* cur_s = (int*)alloc((size_t)NF * 4);
  int* cur_p = (int*)alloc((size_t)NF * 4);
  int* cur_r = (int*)alloc((size_t)NH * 4);
  int* cur_q = (int*)alloc((size_t)NH * 4);
  int* csr_s = (int*)alloc((size_t)Es * 4);
  int* csr_p = (int*)alloc((size_t)Ep * 4);
  int* csr_r = (int*)alloc((size_t)Erv * 4);
  int* csr_q = (int*)alloc((size_t)Erc * 4);
  int* ssum  = (int*)alloc(1024 * 4);

  size_t cnt_bytes = (char*)cnt_q + (size_t)NH*4 - (char*)cnt_s;
  hipMemsetAsync(cnt_s, 0, cnt_bytes, stream);
  hipMemsetAsync(stats, 0, 1024 * 4, stream);

  k_prep<<<(4*128*384 + 512 + 255)/256, 256, 0, stream>>>(Wl, bl, Wr, wcat, bcat);
  k_cvt<<<1024, 256, 0, stream>>>(x_flow, xf16, NF * FH / 4);
  k_cvt<<<1024, 256, 0, stream>>>(x_host, xh16, NH * FH / 4);

  k_hist<<<(Es +255)/256, 256, 0, stream>>>(ei_s  + Es,  Es,  cnt_s);
  k_hist<<<(Ep +255)/256, 256, 0, stream>>>(ei_p  + Ep,  Ep,  cnt_p);
  k_hist<<<(Erv+255)/256, 256, 0, stream>>>(ei_rv + Erv, Erv, cnt_r);
  k_hist<<<(Erc+255)/256, 256, 0, stream>>>(ei_rc + Erc, Erc, cnt_q);

  int nchF = (NF + 1023) / 1024;   // 196
  int nchH = (NH + 1023) / 1024;   // 49
  dim3 gscan(nchF, 4);
  k_chunk_sums<<<gscan, 256, 0, stream>>>(cnt_s, cnt_p, cnt_r, cnt_q, NF, NF, NH, NH, ssum);
  k_scan_sums<<<4, 256, 0, stream>>>(ssum, nchF, nchF, nchH, nchH);
  k_write_offsets<<<gscan, 256, 0, stream>>>(cnt_s, cnt_p, cnt_r, cnt_q,
                                             off_s, off_p, off_r, off_q,
                                             cur_s, cur_p, cur_r, cur_q,
                                             NF, NF, NH, NH, ssum);

  k_fill<<<(Es +255)/256, 256, 0, stream>>>(ei_s,  ei_s  + Es,  Es,  cur_s, csr_s);
  k_fill<<<(Ep +255)/256, 256, 0, stream>>>(ei_p,  ei_p  + Ep,  Ep,  cur_p, csr_p);
  k_fill<<<(Erv+255)/256, 256, 0, stream>>>(ei_rv, ei_rv + Erv, Erv, cur_r, csr_r);
  k_fill<<<(Erc+255)/256, 256, 0, stream>>>(ei_rc, ei_rc + Erc, Erc, cur_q, csr_q);

  int gF = (NF + 31) / 32;   // 6250
  int gH = (NH + 31) / 32;   // 1563

  for (int blk = 0; blk < 2; ++blk){
    const u16* fcur = blk ? f16_0 : xf16;
    const u16* hcur = blk ? h16_0 : xh16;
    const float* scF = blk ? ssbuf + 0   : nullptr;
    const float* shF = blk ? ssbuf + 128 : nullptr;
    const float* scH = blk ? ssbuf + 256 : nullptr;
    const float* shH = blk ? ssbuf + 384 : nullptr;
    float* oF32 = blk ? out_f : nullptr;
    float* oH32 = blk ? out_h : nullptr;
    u16*   oF16 = blk ? nullptr : f16_0;
    u16*   oH16 = blk ? nullptr : h16_0;
    const u16* wf = wcat + (size_t)(blk*2 + 0) * 49152;
    const u16* wh = wcat + (size_t)(blk*2 + 1) * 49152;
    const float* bf = bcat + (blk*2 + 0) * 128;
    const float* bh = bcat + (blk*2 + 1) * 128;

    k_gemm<<<gF, 256, 0, stream>>>(NF,
        off_s, csr_s, hcur, scH, shH,
        off_p, csr_p, fcur, scF, shF,
        fcur, scF, shF,
        wf, bf, oF32, oF16);
    k_gemm<<<gH, 256, 0, stream>>>(NH,
        off_r, csr_r, fcur, scF, shF,
        off_q, csr_q, fcur, scF, shF,
        hcur, scH, shH,
        wh, bh, oH32, oH16);

    float* st = stats + blk * 512;
    if (blk == 0){
      k_bn_stats16<<<512, 256, 0, stream>>>(f16_0, NF, st + 0,   st + 128);
      k_bn_stats16<<<512, 256, 0, stream>>>(h16_0, NH, st + 256, st + 384);
    } else {
      k_bn_stats<<<512, 256, 0, stream>>>(out_f, NF, st + 0,   st + 128);
      k_bn_stats<<<512, 256, 0, stream>>>(out_h, NH, st + 256, st + 384);
    }
    float* ss = ssbuf + blk * 512;
    k_bn_finalize<<<1, 256, 0, stream>>>(st + 0, st + 128, 1.f/(float)NF,
                                         st + 256, st + 384, 1.f/(float)NH,
                                         gamma + blk*128, beta + blk*128,
                                         ss + 0, ss + 128, ss + 256, ss + 384);
  }

  k_apply<<<2048, 256, 0, stream>>>(out_f, NF * FH / 4, ssbuf + 512 + 0,   ssbuf + 512 + 128);
  k_apply<<<2048, 256, 0, stream>>>(out_h, NH * FH / 4, ssbuf + 512 + 256, ssbuf + 512 + 384);
}

// Round 5
// 1861.355 us; speedup vs baseline: 1.0636x; 1.0364x over previous
//
#include <hip/hip_runtime.h>

#define FH 128
#define NEG 0.01f
#define BNEPS 1e-5f

typedef unsigned int uint32;
typedef unsigned short u16;
typedef __attribute__((ext_vector_type(8))) short bf16x8;
typedef __attribute__((ext_vector_type(4))) float f32x4;

__device__ __forceinline__ float lrelu(float v){ return v >= 0.f ? v : NEG * v; }
__device__ __forceinline__ float bfl(uint32 u){ return __uint_as_float(u << 16); }
__device__ __forceinline__ float bfh(uint32 u){ return __uint_as_float(u & 0xffff0000u); }
__device__ __forceinline__ u16 f2bf(float f){
  uint32 u = __float_as_uint(f);
  u += 0x7fffu + ((u >> 16) & 1u);   // RNE
  return (u16)(u >> 16);
}

// ---------------- fp32 -> bf16 table conversion ----------------
__global__ void k_cvt(const float* __restrict__ x, u16* __restrict__ t, int n4){
  int g = blockIdx.x * 256 + threadIdx.x;
  int stride = gridDim.x * 256;
  for (int i = g; i < n4; i += stride){
    float4 v = ((const float4*)x)[i];
    ushort4 p;
    p.x = f2bf(v.x); p.y = f2bf(v.y); p.z = f2bf(v.z); p.w = f2bf(v.w);
    ((ushort4*)t)[i] = p;
  }
}

// ---------------- CSR build ----------------
__global__ void k_hist(const int* __restrict__ dst, int E, int* __restrict__ cnt){
  int i = blockIdx.x * 256 + threadIdx.x;
  if (i < E) atomicAdd(&cnt[dst[i]], 1);
}

__global__ void k_fill(const int* __restrict__ src, const int* __restrict__ dst, int E,
                       int* __restrict__ cur, int* __restrict__ csr){
  int i = blockIdx.x * 256 + threadIdx.x;
  if (i < E){
    int slot = atomicAdd(&cur[dst[i]], 1);
    csr[slot] = src[i];
  }
}

__global__ void k_chunk_sums(const int* c0, const int* c1, const int* c2, const int* c3,
                             int l0, int l1, int l2, int l3, int* __restrict__ sums){
  int a = blockIdx.y;
  const int* c = a==0?c0 : a==1?c1 : a==2?c2 : c3;
  int len     = a==0?l0 : a==1?l1 : a==2?l2 : l3;
  int base = blockIdx.x * 1024;
  if (base >= len) return;
  int t = threadIdx.x;
  int s = 0;
  #pragma unroll
  for (int u = 0; u < 4; ++u){ int i = base + t*4 + u; if (i < len) s += c[i]; }
  __shared__ int red[256];
  red[t] = s; __syncthreads();
  for (int o = 128; o > 0; o >>= 1){ if (t < o) red[t] += red[t+o]; __syncthreads(); }
  if (t == 0) sums[a*256 + blockIdx.x] = red[0];
}

__global__ void k_scan_sums(int* sums, int n0, int n1, int n2, int n3){
  int a = blockIdx.x;
  int n = a==0?n0 : a==1?n1 : a==2?n2 : n3;
  int t = threadIdx.x;
  __shared__ int shm[256];
  shm[t] = (t < n) ? sums[a*256 + t] : 0;
  __syncthreads();
  for (int o = 1; o < 256; o <<= 1){
    int x = shm[t];
    if (t >= o) x += shm[t-o];
    __syncthreads();
    shm[t] = x;
    __syncthreads();
  }
  sums[a*256 + t] = t ? shm[t-1] : 0;
}

__global__ void k_write_offsets(const int* c0, const int* c1, const int* c2, const int* c3,
                                int* o0, int* o1, int* o2, int* o3,
                                int* u0, int* u1, int* u2, int* u3,
                                int l0, int l1, int l2, int l3,
                                const int* __restrict__ sums){
  int a = blockIdx.y;
  const int* c = a==0?c0 : a==1?c1 : a==2?c2 : c3;
  int* off     = a==0?o0 : a==1?o1 : a==2?o2 : o3;
  int* cur     = a==0?u0 : a==1?u1 : a==2?u2 : u3;
  int len      = a==0?l0 : a==1?l1 : a==2?l2 : l3;
  int base = blockIdx.x * 1024;
  if (base >= len) return;
  int t = threadIdx.x;
  int v[4]; int s = 0;
  #pragma unroll
  for (int u = 0; u < 4; ++u){ int i = base + t*4 + u; v[u] = (i < len) ? c[i] : 0; s += v[u]; }
  __shared__ int shm[256];
  shm[t] = s; __syncthreads();
  for (int o = 1; o < 256; o <<= 1){
    int x = shm[t];
    if (t >= o) x += shm[t-o];
    __syncthreads();
    shm[t] = x;
    __syncthreads();
  }
  int run = (t ? shm[t-1] : 0) + sums[a*256 + blockIdx.x];
  #pragma unroll
  for (int u = 0; u < 4; ++u){
    int i = base + t*4 + u;
    if (i < len){
      off[i] = run; cur[i] = run; run += v[u];
      if (i == len - 1) off[len] = run;
    }
  }
}

// ---------------- weight concat (bf16, transposed: Wt[which][c][k]) ----------------
__global__ void k_prep(const float* __restrict__ Wl, const float* __restrict__ bl,
                       const float* __restrict__ Wr, u16* __restrict__ wt,
                       float* __restrict__ bcat){
  int g = blockIdx.x * 256 + threadIdx.x;
  const int NW = 4 * 128 * 384;
  if (g < NW){
    int which = g / 49152;          // blk*2 + side
    int blk = which >> 1, side = which & 1;
    int idx = g % 49152;
    int c = idx / 384;              // out col 0..127
    int k = idx % 384;              // 0..383
    int part = k >> 7, kk = k & 127;
    int tA = side == 0 ? 0 : 1;
    int tB = side == 0 ? 2 : 3;
    float v;
    if (part == 0)      v = 0.5f * Wl[(((blk*4 + tA)*128 + c)*128) + kk];
    else if (part == 1) v = 0.5f * Wl[(((blk*4 + tB)*128 + c)*128) + kk];
    else v = 0.5f * (Wr[(((blk*4 + tA)*128 + c)*128) + kk] + Wr[(((blk*4 + tB)*128 + c)*128) + kk]);
    wt[g] = f2bf(v);
  } else if (g < NW + 512){
    int i = g - NW;
    int which = i >> 7;
    int blk = which >> 1, side = which & 1;
    int c = i & 127;
    int tA = side == 0 ? 0 : 1;
    int tB = side == 0 ? 2 : 3;
    bcat[which*128 + c] = 0.5f * (bl[(blk*4 + tA)*128 + c] + bl[(blk*4 + tB)*128 + c]);
  }
}

// ---- edge-chunk accumulate: EXACT round-4 summation order (vx even / ux odd) ----
__device__ __forceinline__ void acc_chunk(
    float& vx, float& vy, float& ux, float& uy,
    int vidx, int rem, const u16* __restrict__ tab, int lane, bool bn,
    float scx, float scy, float shx, float shy)
{
  int i = 0;
  if (bn){
    for (; i + 8 <= rem; i += 8){
      int t0 = __shfl(vidx, i),   t1 = __shfl(vidx, i+1);
      int t2 = __shfl(vidx, i+2), t3 = __shfl(vidx, i+3);
      int t4 = __shfl(vidx, i+4), t5 = __shfl(vidx, i+5);
      int t6 = __shfl(vidx, i+6), t7 = __shfl(vidx, i+7);
      uint32 x0 = *(const uint32*)(tab + (size_t)t0*FH + 2*lane);
      uint32 x1 = *(const uint32*)(tab + (size_t)t1*FH + 2*lane);
      uint32 x2 = *(const uint32*)(tab + (size_t)t2*FH + 2*lane);
      uint32 x3 = *(const uint32*)(tab + (size_t)t3*FH + 2*lane);
      uint32 x4 = *(const uint32*)(tab + (size_t)t4*FH + 2*lane);
      uint32 x5 = *(const uint32*)(tab + (size_t)t5*FH + 2*lane);
      uint32 x6 = *(const uint32*)(tab + (size_t)t6*FH + 2*lane);
      uint32 x7 = *(const uint32*)(tab + (size_t)t7*FH + 2*lane);
      vx += lrelu(fmaf(bfl(x0), scx, shx)); vy += lrelu(fmaf(bfh(x0), scy, shy));
      ux += lrelu(fmaf(bfl(x1), scx, shx)); uy += lrelu(fmaf(bfh(x1), scy, shy));
      vx += lrelu(fmaf(bfl(x2), scx, shx)); vy += lrelu(fmaf(bfh(x2), scy, shy));
      ux += lrelu(fmaf(bfl(x3), scx, shx)); uy += lrelu(fmaf(bfh(x3), scy, shy));
      vx += lrelu(fmaf(bfl(x4), scx, shx)); vy += lrelu(fmaf(bfh(x4), scy, shy));
      ux += lrelu(fmaf(bfl(x5), scx, shx)); uy += lrelu(fmaf(bfh(x5), scy, shy));
      vx += lrelu(fmaf(bfl(x6), scx, shx)); vy += lrelu(fmaf(bfh(x6), scy, shy));
      ux += lrelu(fmaf(bfl(x7), scx, shx)); uy += lrelu(fmaf(bfh(x7), scy, shy));
    }
    for (; i + 4 <= rem; i += 4){
      int s0 = __shfl(vidx, i),   s1 = __shfl(vidx, i+1);
      int s2 = __shfl(vidx, i+2), s3 = __shfl(vidx, i+3);
      uint32 x0 = *(const uint32*)(tab + (size_t)s0*FH + 2*lane);
      uint32 x1 = *(const uint32*)(tab + (size_t)s1*FH + 2*lane);
      uint32 x2 = *(const uint32*)(tab + (size_t)s2*FH + 2*lane);
      uint32 x3 = *(const uint32*)(tab + (size_t)s3*FH + 2*lane);
      vx += lrelu(fmaf(bfl(x0), scx, shx)); vy += lrelu(fmaf(bfh(x0), scy, shy));
      ux += lrelu(fmaf(bfl(x1), scx, shx)); uy += lrelu(fmaf(bfh(x1), scy, shy));
      vx += lrelu(fmaf(bfl(x2), scx, shx)); vy += lrelu(fmaf(bfh(x2), scy, shy));
      ux += lrelu(fmaf(bfl(x3), scx, shx)); uy += lrelu(fmaf(bfh(x3), scy, shy));
    }
    for (; i < rem; ++i){
      int s0 = __shfl(vidx, i);
      uint32 x0 = *(const uint32*)(tab + (size_t)s0*FH + 2*lane);
      vx += lrelu(fmaf(bfl(x0), scx, shx)); vy += lrelu(fmaf(bfh(x0), scy, shy));
    }
  } else {
    for (; i + 8 <= rem; i += 8){
      int t0 = __shfl(vidx, i),   t1 = __shfl(vidx, i+1);
      int t2 = __shfl(vidx, i+2), t3 = __shfl(vidx, i+3);
      int t4 = __shfl(vidx, i+4), t5 = __shfl(vidx, i+5);
      int t6 = __shfl(vidx, i+6), t7 = __shfl(vidx, i+7);
      uint32 x0 = *(const uint32*)(tab + (size_t)t0*FH + 2*lane);
      uint32 x1 = *(const uint32*)(tab + (size_t)t1*FH + 2*lane);
      uint32 x2 = *(const uint32*)(tab + (size_t)t2*FH + 2*lane);
      uint32 x3 = *(const uint32*)(tab + (size_t)t3*FH + 2*lane);
      uint32 x4 = *(const uint32*)(tab + (size_t)t4*FH + 2*lane);
      uint32 x5 = *(const uint32*)(tab + (size_t)t5*FH + 2*lane);
      uint32 x6 = *(const uint32*)(tab + (size_t)t6*FH + 2*lane);
      uint32 x7 = *(const uint32*)(tab + (size_t)t7*FH + 2*lane);
      vx += bfl(x0); vy += bfh(x0);
      ux += bfl(x1); uy += bfh(x1);
      vx += bfl(x2); vy += bfh(x2);
      ux += bfl(x3); uy += bfh(x3);
      vx += bfl(x4); vy += bfh(x4);
      ux += bfl(x5); uy += bfh(x5);
      vx += bfl(x6); vy += bfh(x6);
      ux += bfl(x7); uy += bfh(x7);
    }
    for (; i + 4 <= rem; i += 4){
      int s0 = __shfl(vidx, i),   s1 = __shfl(vidx, i+1);
      int s2 = __shfl(vidx, i+2), s3 = __shfl(vidx, i+3);
      uint32 x0 = *(const uint32*)(tab + (size_t)s0*FH + 2*lane);
      uint32 x1 = *(const uint32*)(tab + (size_t)s1*FH + 2*lane);
      uint32 x2 = *(const uint32*)(tab + (size_t)s2*FH + 2*lane);
      uint32 x3 = *(const uint32*)(tab + (size_t)s3*FH + 2*lane);
      vx += bfl(x0); vy += bfh(x0);
      ux += bfl(x1); uy += bfh(x1);
      vx += bfl(x2); vy += bfh(x2);
      ux += bfl(x3); uy += bfh(x3);
    }
    for (; i < rem; ++i){
      int s0 = __shfl(vidx, i);
      uint32 x0 = *(const uint32*)(tab + (size_t)s0*FH + 2*lane);
      vx += bfl(x0); vy += bfh(x0);
    }
  }
}

// ---------------- fused gather-mean + MFMA GEMM ----------------
// 32 rows x 128 cols per block. Staging restructured to kill serial index
// chains: (1) off[] for all 8 wave-rows fetched in ONE vector load + shfl,
// (2) csr chunks prefetched into registers two rows ahead (software pipeline),
// so edge-load bursts of consecutive rows issue back-to-back. Summation order
// is bit-identical to the round-4 kernel (acc_chunk, chunk-relative parity).
__global__ __launch_bounds__(256, 6) void k_gemm(
    int M,
    const int* __restrict__ off0, const int* __restrict__ csr0, const u16* __restrict__ tab0,
    const float* __restrict__ sc0, const float* __restrict__ sh0,
    const int* __restrict__ off1, const int* __restrict__ csr1, const u16* __restrict__ tab1,
    const float* __restrict__ sc1, const float* __restrict__ sh1,
    const u16* __restrict__ tabd, const float* __restrict__ scd, const float* __restrict__ shd,
    const u16* __restrict__ Wt, const float* __restrict__ bias,
    float* __restrict__ out32, u16* __restrict__ out16)
{
  __shared__ u16 As[32][392];     // 392 = 384 + 8 pad -> 16B-unit stride 49 (odd): 2-way max
  const int tid = threadIdx.x;
  const int row0 = blockIdx.x * 32;
  const int lane = tid & 63;
  const int wave = tid >> 6;
  const int rbase = row0 + (wave << 3);

  // ---- gather parts 0,1 ----
  for (int part = 0; part < 2; ++part){
    const int* off = part ? off1 : off0;
    const int* csr = part ? csr1 : csr0;
    const u16* tab = part ? tab1 : tab0;
    const float* sc = part ? sc1 : sc0;
    const float* sh = part ? sh1 : sh0;
    const bool bn = (sc != nullptr);
    float scx = 1.f, scy = 1.f, shx = 0.f, shy = 0.f;
    if (bn){
      scx = sc[2*lane]; scy = sc[2*lane+1];
      shx = sh[2*lane]; shy = sh[2*lane+1];
    }

    // one vector load covers off[rbase .. rbase+8] (9 values, lanes 0..8)
    int oidx = rbase + lane;
    int offv = 0;
    if (lane < 9) offv = off[oidx <= M ? oidx : M];

    // prefetch csr chunks for rows 0,1
    int sA = __shfl(offv, 0), eA = __shfl(offv, 1);
    int sB = eA,              eB = __shfl(offv, 2);
    int vA = 0, vB = 0;
    if (sA + lane < eA) vA = csr[sA + lane];
    if (sB + lane < eB) vB = csr[sB + lane];

    for (int g = 0; g < 4; ++g){
      int rA = 2*g, rB = 2*g + 1;
      int sAc = __shfl(offv, rA), eAc = __shfl(offv, rA+1);
      int sBc = eAc,              eBc = __shfl(offv, rB+1);

      // prefetch next pair (rows rA+2, rB+2) before processing current
      int vNA = 0, vNB = 0;
      if (g < 3){
        int sNA = __shfl(offv, rA+2), eNA = __shfl(offv, rA+3);
        int sNB = eNA,                eNB = __shfl(offv, rA+4);
        if (sNA + lane < eNA) vNA = csr[sNA + lane];
        if (sNB + lane < eNB) vNB = csr[sNB + lane];
      }

      // ---- row A ----
      {
        int r = (wave << 3) + rA;
        int row = row0 + r;
        float vx = 0.f, vy = 0.f;
        if (row < M){
          int n = eAc - sAc;
          float ux = 0.f, uy = 0.f;
          int rem0 = n > 64 ? 64 : n;
          acc_chunk(vx, vy, ux, uy, vA, rem0, tab, lane, bn, scx, scy, shx, shy);
          for (int base = sAc + 64; base < eAc; base += 64){
            int rem = eAc - base; if (rem > 64) rem = 64;
            int vidx = 0;
            if (base + lane < eAc) vidx = csr[base + lane];
            acc_chunk(vx, vy, ux, uy, vidx, rem, tab, lane, bn, scx, scy, shx, shy);
          }
          float inv = 1.f / (float)(n > 1 ? n : 1);
          vx = (vx + ux) * inv;
          vy = (vy + uy) * inv;
        }
        uint32 pk = ((uint32)f2bf(vy) << 16) | (uint32)f2bf(vx);
        *(uint32*)&As[r][part*128 + 2*lane] = pk;
      }
      // ---- row B ----
      {
        int r = (wave << 3) + rB;
        int row = row0 + r;
        float vx = 0.f, vy = 0.f;
        if (row < M){
          int n = eBc - sBc;
          float ux = 0.f, uy = 0.f;
          int rem0 = n > 64 ? 64 : n;
          acc_chunk(vx, vy, ux, uy, vB, rem0, tab, lane, bn, scx, scy, shx, shy);
          for (int base = sBc + 64; base < eBc; base += 64){
            int rem = eBc - base; if (rem > 64) rem = 64;
            int vidx = 0;
            if (base + lane < eBc) vidx = csr[base + lane];
            acc_chunk(vx, vy, ux, uy, vidx, rem, tab, lane, bn, scx, scy, shx, shy);
          }
          float inv = 1.f / (float)(n > 1 ? n : 1);
          vx = (vx + ux) * inv;
          vy = (vy + uy) * inv;
        }
        uint32 pk = ((uint32)f2bf(vy) << 16) | (uint32)f2bf(vx);
        *(uint32*)&As[r][part*128 + 2*lane] = pk;
      }
      vA = vNA; vB = vNB;
    }
  }

  // ---- self part (part 2) ----
  {
    const bool bn = (scd != nullptr);
    float scx = 1.f, scy = 1.f, shx = 0.f, shy = 0.f;
    if (bn){
      scx = scd[2*lane]; scy = scd[2*lane+1];
      shx = shd[2*lane]; shy = shd[2*lane+1];
    }
    for (int rr = 0; rr < 8; ++rr){
      int r = (wave << 3) + rr;
      int row = row0 + r;
      float vx = 0.f, vy = 0.f;
      if (row < M){
        uint32 x = *(const uint32*)(tabd + (size_t)row*FH + 2*lane);
        float fx = bfl(x), fy = bfh(x);
        if (bn){
          vx = lrelu(fmaf(fx, scx, shx));
          vy = lrelu(fmaf(fy, scy, shy));
        } else { vx = fx; vy = fy; }
      }
      uint32 pk = ((uint32)f2bf(vy) << 16) | (uint32)f2bf(vx);
      *(uint32*)&As[r][256 + 2*lane] = pk;
    }
  }
  __syncthreads();

  // ---- MFMA: wave = 16 rows x 64 cols; K = 384 ----
  const int rowtile = wave >> 1;      // 0..1
  const int colhalf = wave & 1;       // 0..1
  const int qm  = lane & 15;
  const int quad = lane >> 4;
  f32x4 acc[4] = {{0,0,0,0},{0,0,0,0},{0,0,0,0},{0,0,0,0}};
  const u16* abase = &As[rowtile*16 + qm][quad*8];
  const u16* wbase = Wt + ((size_t)(colhalf*64 + qm) * 384 + quad*8);

  #pragma unroll
  for (int k0 = 0; k0 < 384; k0 += 32){
    bf16x8 a  = *(const bf16x8*)(abase + k0);
    bf16x8 b0 = *(const bf16x8*)(wbase + 0*16*384 + k0);
    bf16x8 b1 = *(const bf16x8*)(wbase + 1*16*384 + k0);
    bf16x8 b2 = *(const bf16x8*)(wbase + 2*16*384 + k0);
    bf16x8 b3 = *(const bf16x8*)(wbase + 3*16*384 + k0);
    acc[0] = __builtin_amdgcn_mfma_f32_16x16x32_bf16(a, b0, acc[0], 0, 0, 0);
    acc[1] = __builtin_amdgcn_mfma_f32_16x16x32_bf16(a, b1, acc[1], 0, 0, 0);
    acc[2] = __builtin_amdgcn_mfma_f32_16x16x32_bf16(a, b2, acc[2], 0, 0, 0);
    acc[3] = __builtin_amdgcn_mfma_f32_16x16x32_bf16(a, b3, acc[3], 0, 0, 0);
  }

  // ---- epilogue: D[m=quad*4+reg][n=qm] ----
  #pragma unroll
  for (int f = 0; f < 4; ++f){
    int col = colhalf*64 + f*16 + qm;
    float bi = bias[col];
    #pragma unroll
    for (int reg = 0; reg < 4; ++reg){
      int row = row0 + rowtile*16 + quad*4 + reg;
      if (row < M){
        float o = acc[f][reg] + bi;
        if (out32) out32[(size_t)row*FH + col] = o;
        if (out16) out16[(size_t)row*FH + col] = f2bf(o);
      }
    }
  }
}

// ---------------- BN ----------------
__global__ void k_bn_stats(const float* __restrict__ x, int M,
                           float* __restrict__ gsum, float* __restrict__ gsq){
  int t = threadIdx.x;
  int f = t & 127;
  int half = t >> 7;
  float s = 0.f, q = 0.f;
  for (int row = blockIdx.x*2 + half; row < M; row += gridDim.x*2){
    float v = x[(size_t)row*FH + f];
    s += v; q += v*v;
  }
  __shared__ float red[256];
  red[t] = s; __syncthreads();
  if (t < 128) atomicAdd(&gsum[t], red[t] + red[t+128]);
  __syncthreads();
  red[t] = q; __syncthreads();
  if (t < 128) atomicAdd(&gsq[t], red[t] + red[t+128]);
}

__global__ void k_bn_stats16(const u16* __restrict__ x, int M,
                             float* __restrict__ gsum, float* __restrict__ gsq){
  int t = threadIdx.x;
  int f = t & 127;
  int half = t >> 7;
  float s = 0.f, q = 0.f;
  for (int row = blockIdx.x*2 + half; row < M; row += gridDim.x*2){
    float v = __uint_as_float(((uint32)x[(size_t)row*FH + f]) << 16);
    s += v; q += v*v;
  }
  __shared__ float red[256];
  red[t] = s; __syncthreads();
  if (t < 128) atomicAdd(&gsum[t], red[t] + red[t+128]);
  __syncthreads();
  red[t] = q; __syncthreads();
  if (t < 128) atomicAdd(&gsq[t], red[t] + red[t+128]);
}

__global__ void k_bn_finalize(const float* __restrict__ sF, const float* __restrict__ qF, float invMF,
                              const float* __restrict__ sH, const float* __restrict__ qH, float invMH,
                              const float* __restrict__ gamma, const float* __restrict__ beta,
                              float* scF, float* shF, float* scH, float* shH){
  int t = threadIdx.x;
  if (t < 128){
    float mu = sF[t] * invMF;
    float var = qF[t] * invMF - mu*mu;
    float s = gamma[t] * rsqrtf(var + BNEPS);
    scF[t] = s; shF[t] = beta[t] - mu*s;
  } else {
    int f = t - 128;
    float mu = sH[f] * invMH;
    float var = qH[f] * invMH - mu*mu;
    float s = gamma[f] * rsqrtf(var + BNEPS);
    scH[f] = s; shH[f] = beta[f] - mu*s;
  }
}

__global__ void k_apply(float* __restrict__ x, int n4,
                        const float* __restrict__ sc, const float* __restrict__ shf){
  int g = blockIdx.x * blockDim.x + threadIdx.x;
  int stride = gridDim.x * blockDim.x;
  for (int i = g; i < n4; i += stride){
    float4 v = ((const float4*)x)[i];
    int f = (i*4) & 127;
    float4 s = *(const float4*)(sc + f);
    float4 b = *(const float4*)(shf + f);
    v.x = lrelu(fmaf(v.x, s.x, b.x));
    v.y = lrelu(fmaf(v.y, s.y, b.y));
    v.z = lrelu(fmaf(v.z, s.z, b.z));
    v.w = lrelu(fmaf(v.w, s.w, b.w));
    ((float4*)x)[i] = v;
  }
}

// ---------------- launch ----------------
extern "C" void kernel_launch(void* const* d_in, const int* in_sizes, int n_in,
                              void* d_out, int out_size, void* d_ws, size_t ws_size,
                              hipStream_t stream) {
  const float* x_host = (const float*)d_in[0];
  const float* x_flow = (const float*)d_in[1];
  const int* ei_s  = (const int*)d_in[2];
  const int* ei_rv = (const int*)d_in[3];
  const int* ei_p  = (const int*)d_in[4];
  const int* ei_rc = (const int*)d_in[5];
  const float* Wl    = (const float*)d_in[6];
  const float* bl    = (const float*)d_in[7];
  const float* Wr    = (const float*)d_in[8];
  const float* gamma = (const float*)d_in[9];
  const float* beta  = (const float*)d_in[10];

  const int NH = in_sizes[0] / FH;   // 50000
  const int NF = in_sizes[1] / FH;   // 200000
  const int Es  = in_sizes[2] / 2;
  const int Erv = in_sizes[3] / 2;
  const int Ep  = in_sizes[4] / 2;
  const int Erc = in_sizes[5] / 2;

  float* out_h = (float*)d_out;
  float* out_f = (float*)d_out + (size_t)NH * FH;

  char* p = (char*)d_ws;
  auto alloc = [&](size_t bytes) -> void* {
    void* r = (void*)p;
    p += (bytes + 255) & ~(size_t)255;
    return r;
  };
  u16* xf16  = (u16*)alloc((size_t)NF * FH * 2);  // bf16 input tables
  u16* xh16  = (u16*)alloc((size_t)NH * FH * 2);
  u16* f16_0 = (u16*)alloc((size_t)NF * FH * 2);  // block-0 raw outputs (bf16)
  u16* h16_0 = (u16*)alloc((size_t)NH * FH * 2);
  u16* wcat  = (u16*)alloc((size_t)4 * 49152 * 2); // bf16 Wt[which][c][k]
  float* bcat   = (float*)alloc(512 * 4);
  float* stats  = (float*)alloc(1024 * 4);
  float* ssbuf  = (float*)alloc(1024 * 4);
  int* cnt_s = (int*)alloc((size_t)NF * 4);
  int* cnt_p = (int*)alloc((size_t)NF * 4);
  int* cnt_r = (int*)alloc((size_t)NH * 4);
  int* cnt_q = (int*)alloc((size_t)NH * 4);
  int* off_s = (int*)alloc((size_t)(NF+1) * 4);
  int* off_p = (int*)alloc((size_t)(NF+1) * 4);
  int* off_r = (int*)alloc((size_t)(NH+1) * 4);
  int* off_q = (int*)alloc((size_t)(NH+1) * 4);
  int* cur_s = (int*)alloc((size_t)NF * 4);
  int* cur_p = (int*)alloc((size_t)NF * 4);
  int* cur_r = (int*)alloc((size_t)NH * 4);
  int* cur_q = (int*)alloc((size_t)NH * 4);
  int* csr_s = (int*)alloc((size_t)Es * 4);
  int* csr_p = (int*)alloc((size_t)Ep * 4);
  int* csr_r = (int*)alloc((size_t)Erv * 4);
  int* csr_q = (int*)alloc((size_t)Erc * 4);
  int* ssum  = (int*)alloc(1024 * 4);

  size_t cnt_bytes = (char*)cnt_q + (size_t)NH*4 - (char*)cnt_s;
  hipMemsetAsync(cnt_s, 0, cnt_bytes, stream);
  hipMemsetAsync(stats, 0, 1024 * 4, stream);

  k_prep<<<(4*128*384 + 512 + 255)/256, 256, 0, stream>>>(Wl, bl, Wr, wcat, bcat);
  k_cvt<<<1024, 256, 0, stream>>>(x_flow, xf16, NF * FH / 4);
  k_cvt<<<1024, 256, 0, stream>>>(x_host, xh16, NH * FH / 4);

  k_hist<<<(Es +255)/256, 256, 0, stream>>>(ei_s  + Es,  Es,  cnt_s);
  k_hist<<<(Ep +255)/256, 256, 0, stream>>>(ei_p  + Ep,  Ep,  cnt_p);
  k_hist<<<(Erv+255)/256, 256, 0, stream>>>(ei_rv + Erv, Erv, cnt_r);
  k_hist<<<(Erc+255)/256, 256, 0, stream>>>(ei_rc + Erc, Erc, cnt_q);

  int nchF = (NF + 1023) / 1024;   // 196
  int nchH = (NH + 1023) / 1024;   // 49
  dim3 gscan(nchF, 4);
  k_chunk_sums<<<gscan, 256, 0, stream>>>(cnt_s, cnt_p, cnt_r, cnt_q, NF, NF, NH, NH, ssum);
  k_scan_sums<<<4, 256, 0, stream>>>(ssum, nchF, nchF, nchH, nchH);
  k_write_offsets<<<gscan, 256, 0, stream>>>(cnt_s, cnt_p, cnt_r, cnt_q,
                                             off_s, off_p, off_r, off_q,
                                             cur_s, cur_p, cur_r, cur_q,
                                             NF, NF, NH, NH, ssum);

  k_fill<<<(Es +255)/256, 256, 0, stream>>>(ei_s,  ei_s  + Es,  Es,  cur_s, csr_s);
  k_fill<<<(Ep +255)/256, 256, 0, stream>>>(ei_p,  ei_p  + Ep,  Ep,  cur_p, csr_p);
  k_fill<<<(Erv+255)/256, 256, 0, stream>>>(ei_rv, ei_rv + Erv, Erv, cur_r, csr_r);
  k_fill<<<(Erc+255)/256, 256, 0, stream>>>(ei_rc, ei_rc + Erc, Erc, cur_q, csr_q);

  int gF = (NF + 31) / 32;   // 6250
  int gH = (NH + 31) / 32;   // 1563

  for (int blk = 0; blk < 2; ++blk){
    const u16* fcur = blk ? f16_0 : xf16;
    const u16* hcur = blk ? h16_0 : xh16;
    const float* scF = blk ? ssbuf + 0   : nullptr;
    const float* shF = blk ? ssbuf + 128 : nullptr;
    const float* scH = blk ? ssbuf + 256 : nullptr;
    const float* shH = blk ? ssbuf + 384 : nullptr;
    float* oF32 = blk ? out_f : nullptr;
    float* oH32 = blk ? out_h : nullptr;
    u16*   oF16 = blk ? nullptr : f16_0;
    u16*   oH16 = blk ? nullptr : h16_0;
    const u16* wf = wcat + (size_t)(blk*2 + 0) * 49152;
    const u16* wh = wcat + (size_t)(blk*2 + 1) * 49152;
    const float* bf = bcat + (blk*2 + 0) * 128;
    const float* bh = bcat + (blk*2 + 1) * 128;

    k_gemm<<<gF, 256, 0, stream>>>(NF,
        off_s, csr_s, hcur, scH, shH,
        off_p, csr_p, fcur, scF, shF,
        fcur, scF, shF,
        wf, bf, oF32, oF16);
    k_gemm<<<gH, 256, 0, stream>>>(NH,
        off_r, csr_r, fcur, scF, shF,
        off_q, csr_q, fcur, scF, shF,
        hcur, scH, shH,
        wh, bh, oH32, oH16);

    float* st = stats + blk * 512;
    if (blk == 0){
      k_bn_stats16<<<512, 256, 0, stream>>>(f16_0, NF, st + 0,   st + 128);
      k_bn_stats16<<<512, 256, 0, stream>>>(h16_0, NH, st + 256, st + 384);
    } else {
      k_bn_stats<<<512, 256, 0, stream>>>(out_f, NF, st + 0,   st + 128);
      k_bn_stats<<<512, 256, 0, stream>>>(out_h, NH, st + 256, st + 384);
    }
    float* ss = ssbuf + blk * 512;
    k_bn_finalize<<<1, 256, 0, stream>>>(st + 0, st + 128, 1.f/(float)NF,
                                         st + 256, st + 384, 1.f/(float)NH,
                                         gamma + blk*128, beta + blk*128,
                                         ss + 0, ss + 128, ss + 256, ss + 384);
  }

  k_apply<<<2048, 256, 0, stream>>>(out_f, NF * FH / 4, ssbuf + 512 + 0,   ssbuf + 512 + 128);
  k_apply<<<2048, 256, 0, stream>>>(out_h, NH * FH / 4, ssbuf + 512 + 256, ssbuf + 512 + 384);
}

// Round 6
// 1665.593 us; speedup vs baseline: 1.1886x; 1.1175x over previous
//
#include <hip/hip_runtime.h>

#define FH 128
#define NEG 0.01f
#define BNEPS 1e-5f

typedef unsigned int uint32;
typedef unsigned short u16;
typedef __attribute__((ext_vector_type(8))) short bf16x8;
typedef __attribute__((ext_vector_type(4))) float f32x4;

__device__ __forceinline__ float lrelu(float v){ return v >= 0.f ? v : NEG * v; }
__device__ __forceinline__ float bfl(uint32 u){ return __uint_as_float(u << 16); }
__device__ __forceinline__ float bfh(uint32 u){ return __uint_as_float(u & 0xffff0000u); }
__device__ __forceinline__ u16 f2bf(float f){
  uint32 u = __float_as_uint(f);
  u += 0x7fffu + ((u >> 16) & 1u);   // RNE
  return (u16)(u >> 16);
}

// ---------------- fp32 -> bf16 table conversion (both tables, one launch) ----------
__global__ void k_cvt2(const float* __restrict__ xf, u16* __restrict__ tf, int n4F,
                       const float* __restrict__ xh, u16* __restrict__ th, int n4H){
  int g = blockIdx.x * 256 + threadIdx.x;
  int stride = gridDim.x * 256;
  int tot = n4F + n4H;
  for (int i = g; i < tot; i += stride){
    const float4* src; ushort4* dst; int idx;
    if (i < n4F){ src = (const float4*)xf; dst = (ushort4*)tf; idx = i; }
    else        { src = (const float4*)xh; dst = (ushort4*)th; idx = i - n4F; }
    float4 v = src[idx];
    ushort4 p;
    p.x = f2bf(v.x); p.y = f2bf(v.y); p.z = f2bf(v.z); p.w = f2bf(v.w);
    dst[idx] = p;
  }
}

// ---------------- CSR build (4 edge types per launch) ----------------
__global__ void k_hist4(const int* __restrict__ d0, int E0, const int* __restrict__ d1, int E1,
                        const int* __restrict__ d2, int E2, const int* __restrict__ d3, int E3,
                        int* c0, int* c1, int* c2, int* c3){
  int a = blockIdx.y;
  const int* d = a==0?d0 : a==1?d1 : a==2?d2 : d3;
  int E       = a==0?E0 : a==1?E1 : a==2?E2 : E3;
  int* c      = a==0?c0 : a==1?c1 : a==2?c2 : c3;
  int i = blockIdx.x * 256 + threadIdx.x;
  if (i < E) atomicAdd(&c[d[i]], 1);
}

__global__ void k_fill4(const int* __restrict__ s0, const int* __restrict__ d0, int E0,
                        const int* __restrict__ s1, const int* __restrict__ d1, int E1,
                        const int* __restrict__ s2, const int* __restrict__ d2, int E2,
                        const int* __restrict__ s3, const int* __restrict__ d3, int E3,
                        int* u0, int* u1, int* u2, int* u3,
                        int* r0, int* r1, int* r2, int* r3){
  int a = blockIdx.y;
  const int* src = a==0?s0 : a==1?s1 : a==2?s2 : s3;
  const int* dst = a==0?d0 : a==1?d1 : a==2?d2 : d3;
  int E          = a==0?E0 : a==1?E1 : a==2?E2 : E3;
  int* cur       = a==0?u0 : a==1?u1 : a==2?u2 : u3;
  int* csr       = a==0?r0 : a==1?r1 : a==2?r2 : r3;
  int i = blockIdx.x * 256 + threadIdx.x;
  if (i < E){
    int slot = atomicAdd(&cur[dst[i]], 1);
    csr[slot] = src[i];
  }
}

__global__ void k_chunk_sums(const int* c0, const int* c1, const int* c2, const int* c3,
                             int l0, int l1, int l2, int l3, int* __restrict__ sums){
  int a = blockIdx.y;
  const int* c = a==0?c0 : a==1?c1 : a==2?c2 : c3;
  int len     = a==0?l0 : a==1?l1 : a==2?l2 : l3;
  int base = blockIdx.x * 1024;
  if (base >= len) return;
  int t = threadIdx.x;
  int s = 0;
  #pragma unroll
  for (int u = 0; u < 4; ++u){ int i = base + t*4 + u; if (i < len) s += c[i]; }
  __shared__ int red[256];
  red[t] = s; __syncthreads();
  for (int o = 128; o > 0; o >>= 1){ if (t < o) red[t] += red[t+o]; __syncthreads(); }
  if (t == 0) sums[a*256 + blockIdx.x] = red[0];
}

__global__ void k_scan_sums(int* sums, int n0, int n1, int n2, int n3){
  int a = blockIdx.x;
  int n = a==0?n0 : a==1?n1 : a==2?n2 : n3;
  int t = threadIdx.x;
  __shared__ int shm[256];
  shm[t] = (t < n) ? sums[a*256 + t] : 0;
  __syncthreads();
  for (int o = 1; o < 256; o <<= 1){
    int x = shm[t];
    if (t >= o) x += shm[t-o];
    __syncthreads();
    shm[t] = x;
    __syncthreads();
  }
  sums[a*256 + t] = t ? shm[t-1] : 0;
}

__global__ void k_write_offsets(const int* c0, const int* c1, const int* c2, const int* c3,
                                int* o0, int* o1, int* o2, int* o3,
                                int* u0, int* u1, int* u2, int* u3,
                                int l0, int l1, int l2, int l3,
                                const int* __restrict__ sums){
  int a = blockIdx.y;
  const int* c = a==0?c0 : a==1?c1 : a==2?c2 : c3;
  int* off     = a==0?o0 : a==1?o1 : a==2?o2 : o3;
  int* cur     = a==0?u0 : a==1?u1 : a==2?u2 : u3;
  int len      = a==0?l0 : a==1?l1 : a==2?l2 : l3;
  int base = blockIdx.x * 1024;
  if (base >= len) return;
  int t = threadIdx.x;
  int v[4]; int s = 0;
  #pragma unroll
  for (int u = 0; u < 4; ++u){ int i = base + t*4 + u; v[u] = (i < len) ? c[i] : 0; s += v[u]; }
  __shared__ int shm[256];
  shm[t] = s; __syncthreads();
  for (int o = 1; o < 256; o <<= 1){
    int x = shm[t];
    if (t >= o) x += shm[t-o];
    __syncthreads();
    shm[t] = x;
    __syncthreads();
  }
  int run = (t ? shm[t-1] : 0) + sums[a*256 + blockIdx.x];
  #pragma unroll
  for (int u = 0; u < 4; ++u){
    int i = base + t*4 + u;
    if (i < len){
      off[i] = run; cur[i] = run; run += v[u];
      if (i == len - 1) off[len] = run;
    }
  }
}

// ---------------- weight concat (bf16, transposed: Wt[which][c][k]) ----------------
__global__ void k_prep(const float* __restrict__ Wl, const float* __restrict__ bl,
                       const float* __restrict__ Wr, u16* __restrict__ wt,
                       float* __restrict__ bcat){
  int g = blockIdx.x * 256 + threadIdx.x;
  const int NW = 4 * 128 * 384;
  if (g < NW){
    int which = g / 49152;          // blk*2 + side
    int blk = which >> 1, side = which & 1;
    int idx = g % 49152;
    int c = idx / 384;              // out col 0..127
    int k = idx % 384;              // 0..383
    int part = k >> 7, kk = k & 127;
    int tA = side == 0 ? 0 : 1;
    int tB = side == 0 ? 2 : 3;
    float v;
    if (part == 0)      v = 0.5f * Wl[(((blk*4 + tA)*128 + c)*128) + kk];
    else if (part == 1) v = 0.5f * Wl[(((blk*4 + tB)*128 + c)*128) + kk];
    else v = 0.5f * (Wr[(((blk*4 + tA)*128 + c)*128) + kk] + Wr[(((blk*4 + tB)*128 + c)*128) + kk]);
    wt[g] = f2bf(v);
  } else if (g < NW + 512){
    int i = g - NW;
    int which = i >> 7;
    int blk = which >> 1, side = which & 1;
    int c = i & 127;
    int tA = side == 0 ? 0 : 1;
    int tB = side == 0 ? 2 : 3;
    bcat[which*128 + c] = 0.5f * (bl[(blk*4 + tA)*128 + c] + bl[(blk*4 + tB)*128 + c]);
  }
}

// ---- edge-chunk accumulate: EXACT round-5 summation order (vx even / ux odd) ----
__device__ __forceinline__ void acc_chunk(
    float& vx, float& vy, float& ux, float& uy,
    int vidx, int rem, const u16* __restrict__ tab, int lane, bool bn,
    float scx, float scy, float shx, float shy)
{
  int i = 0;
  if (bn){
    for (; i + 8 <= rem; i += 8){
      int t0 = __shfl(vidx, i),   t1 = __shfl(vidx, i+1);
      int t2 = __shfl(vidx, i+2), t3 = __shfl(vidx, i+3);
      int t4 = __shfl(vidx, i+4), t5 = __shfl(vidx, i+5);
      int t6 = __shfl(vidx, i+6), t7 = __shfl(vidx, i+7);
      uint32 x0 = *(const uint32*)(tab + (size_t)t0*FH + 2*lane);
      uint32 x1 = *(const uint32*)(tab + (size_t)t1*FH + 2*lane);
      uint32 x2 = *(const uint32*)(tab + (size_t)t2*FH + 2*lane);
      uint32 x3 = *(const uint32*)(tab + (size_t)t3*FH + 2*lane);
      uint32 x4 = *(const uint32*)(tab + (size_t)t4*FH + 2*lane);
      uint32 x5 = *(const uint32*)(tab + (size_t)t5*FH + 2*lane);
      uint32 x6 = *(const uint32*)(tab + (size_t)t6*FH + 2*lane);
      uint32 x7 = *(const uint32*)(tab + (size_t)t7*FH + 2*lane);
      vx += lrelu(fmaf(bfl(x0), scx, shx)); vy += lrelu(fmaf(bfh(x0), scy, shy));
      ux += lrelu(fmaf(bfl(x1), scx, shx)); uy += lrelu(fmaf(bfh(x1), scy, shy));
      vx += lrelu(fmaf(bfl(x2), scx, shx)); vy += lrelu(fmaf(bfh(x2), scy, shy));
      ux += lrelu(fmaf(bfl(x3), scx, shx)); uy += lrelu(fmaf(bfh(x3), scy, shy));
      vx += lrelu(fmaf(bfl(x4), scx, shx)); vy += lrelu(fmaf(bfh(x4), scy, shy));
      ux += lrelu(fmaf(bfl(x5), scx, shx)); uy += lrelu(fmaf(bfh(x5), scy, shy));
      vx += lrelu(fmaf(bfl(x6), scx, shx)); vy += lrelu(fmaf(bfh(x6), scy, shy));
      ux += lrelu(fmaf(bfl(x7), scx, shx)); uy += lrelu(fmaf(bfh(x7), scy, shy));
    }
    for (; i + 4 <= rem; i += 4){
      int s0 = __shfl(vidx, i),   s1 = __shfl(vidx, i+1);
      int s2 = __shfl(vidx, i+2), s3 = __shfl(vidx, i+3);
      uint32 x0 = *(const uint32*)(tab + (size_t)s0*FH + 2*lane);
      uint32 x1 = *(const uint32*)(tab + (size_t)s1*FH + 2*lane);
      uint32 x2 = *(const uint32*)(tab + (size_t)s2*FH + 2*lane);
      uint32 x3 = *(const uint32*)(tab + (size_t)s3*FH + 2*lane);
      vx += lrelu(fmaf(bfl(x0), scx, shx)); vy += lrelu(fmaf(bfh(x0), scy, shy));
      ux += lrelu(fmaf(bfl(x1), scx, shx)); uy += lrelu(fmaf(bfh(x1), scy, shy));
      vx += lrelu(fmaf(bfl(x2), scx, shx)); vy += lrelu(fmaf(bfh(x2), scy, shy));
      ux += lrelu(fmaf(bfl(x3), scx, shx)); uy += lrelu(fmaf(bfh(x3), scy, shy));
    }
    for (; i < rem; ++i){
      int s0 = __shfl(vidx, i);
      uint32 x0 = *(const uint32*)(tab + (size_t)s0*FH + 2*lane);
      vx += lrelu(fmaf(bfl(x0), scx, shx)); vy += lrelu(fmaf(bfh(x0), scy, shy));
    }
  } else {
    for (; i + 8 <= rem; i += 8){
      int t0 = __shfl(vidx, i),   t1 = __shfl(vidx, i+1);
      int t2 = __shfl(vidx, i+2), t3 = __shfl(vidx, i+3);
      int t4 = __shfl(vidx, i+4), t5 = __shfl(vidx, i+5);
      int t6 = __shfl(vidx, i+6), t7 = __shfl(vidx, i+7);
      uint32 x0 = *(const uint32*)(tab + (size_t)t0*FH + 2*lane);
      uint32 x1 = *(const uint32*)(tab + (size_t)t1*FH + 2*lane);
      uint32 x2 = *(const uint32*)(tab + (size_t)t2*FH + 2*lane);
      uint32 x3 = *(const uint32*)(tab + (size_t)t3*FH + 2*lane);
      uint32 x4 = *(const uint32*)(tab + (size_t)t4*FH + 2*lane);
      uint32 x5 = *(const uint32*)(tab + (size_t)t5*FH + 2*lane);
      uint32 x6 = *(const uint32*)(tab + (size_t)t6*FH + 2*lane);
      uint32 x7 = *(const uint32*)(tab + (size_t)t7*FH + 2*lane);
      vx += bfl(x0); vy += bfh(x0);
      ux += bfl(x1); uy += bfh(x1);
      vx += bfl(x2); vy += bfh(x2);
      ux += bfl(x3); uy += bfh(x3);
      vx += bfl(x4); vy += bfh(x4);
      ux += bfl(x5); uy += bfh(x5);
      vx += bfl(x6); vy += bfh(x6);
      ux += bfl(x7); uy += bfh(x7);
    }
    for (; i + 4 <= rem; i += 4){
      int s0 = __shfl(vidx, i),   s1 = __shfl(vidx, i+1);
      int s2 = __shfl(vidx, i+2), s3 = __shfl(vidx, i+3);
      uint32 x0 = *(const uint32*)(tab + (size_t)s0*FH + 2*lane);
      uint32 x1 = *(const uint32*)(tab + (size_t)s1*FH + 2*lane);
      uint32 x2 = *(const uint32*)(tab + (size_t)s2*FH + 2*lane);
      uint32 x3 = *(const uint32*)(tab + (size_t)s3*FH + 2*lane);
      vx += bfl(x0); vy += bfh(x0);
      ux += bfl(x1); uy += bfh(x1);
      vx += bfl(x2); vy += bfh(x2);
      ux += bfl(x3); uy += bfh(x3);
    }
    for (; i < rem; ++i){
      int s0 = __shfl(vidx, i);
      uint32 x0 = *(const uint32*)(tab + (size_t)s0*FH + 2*lane);
      vx += bfl(x0); vy += bfh(x0);
    }
  }
}

// ---------------- merged gather+GEMM args ----------------
struct GemmArgs {
  int M;
  const int* off0; const int* csr0; const u16* tab0; const float* sc0; const float* sh0;
  const int* off1; const int* csr1; const u16* tab1; const float* sc1; const float* sh1;
  const u16* tabd; const float* scd; const float* shd;
  const u16* Wt; const float* bias;
  float* out32; u16* out16;
  float* gsum; float* gsq;     // fused BN stats accumulators (128 floats each)
};

// Round-5 gather + MFMA body, plus fused BN-stats epilogue.
__device__ __forceinline__ void gemm_body(const GemmArgs& A, int bx, u16 (*As)[392]){
  const int M = A.M;
  const int tid = threadIdx.x;
  const int row0 = bx * 32;
  const int lane = tid & 63;
  const int wave = tid >> 6;
  const int rbase = row0 + (wave << 3);

  // ---- gather parts 0,1 (identical to round 5) ----
  for (int part = 0; part < 2; ++part){
    const int* off = part ? A.off1 : A.off0;
    const int* csr = part ? A.csr1 : A.csr0;
    const u16* tab = part ? A.tab1 : A.tab0;
    const float* sc = part ? A.sc1 : A.sc0;
    const float* sh = part ? A.sh1 : A.sh0;
    const bool bn = (sc != nullptr);
    float scx = 1.f, scy = 1.f, shx = 0.f, shy = 0.f;
    if (bn){
      scx = sc[2*lane]; scy = sc[2*lane+1];
      shx = sh[2*lane]; shy = sh[2*lane+1];
    }

    int oidx = rbase + lane;
    int offv = 0;
    if (lane < 9) offv = off[oidx <= M ? oidx : M];

    int sA = __shfl(offv, 0), eA = __shfl(offv, 1);
    int sB = eA,              eB = __shfl(offv, 2);
    int vA = 0, vB = 0;
    if (sA + lane < eA) vA = csr[sA + lane];
    if (sB + lane < eB) vB = csr[sB + lane];

    for (int g = 0; g < 4; ++g){
      int rA = 2*g, rB = 2*g + 1;
      int sAc = __shfl(offv, rA), eAc = __shfl(offv, rA+1);
      int sBc = eAc,              eBc = __shfl(offv, rB+1);

      int vNA = 0, vNB = 0;
      if (g < 3){
        int sNA = __shfl(offv, rA+2), eNA = __shfl(offv, rA+3);
        int sNB = eNA,                eNB = __shfl(offv, rA+4);
        if (sNA + lane < eNA) vNA = csr[sNA + lane];
        if (sNB + lane < eNB) vNB = csr[sNB + lane];
      }

      {
        int r = (wave << 3) + rA;
        int row = row0 + r;
        float vx = 0.f, vy = 0.f;
        if (row < M){
          int n = eAc - sAc;
          float ux = 0.f, uy = 0.f;
          int rem0 = n > 64 ? 64 : n;
          acc_chunk(vx, vy, ux, uy, vA, rem0, tab, lane, bn, scx, scy, shx, shy);
          for (int base = sAc + 64; base < eAc; base += 64){
            int rem = eAc - base; if (rem > 64) rem = 64;
            int vidx = 0;
            if (base + lane < eAc) vidx = csr[base + lane];
            acc_chunk(vx, vy, ux, uy, vidx, rem, tab, lane, bn, scx, scy, shx, shy);
          }
          float inv = 1.f / (float)(n > 1 ? n : 1);
          vx = (vx + ux) * inv;
          vy = (vy + uy) * inv;
        }
        uint32 pk = ((uint32)f2bf(vy) << 16) | (uint32)f2bf(vx);
        *(uint32*)&As[r][part*128 + 2*lane] = pk;
      }
      {
        int r = (wave << 3) + rB;
        int row = row0 + r;
        float vx = 0.f, vy = 0.f;
        if (row < M){
          int n = eBc - sBc;
          float ux = 0.f, uy = 0.f;
          int rem0 = n > 64 ? 64 : n;
          acc_chunk(vx, vy, ux, uy, vB, rem0, tab, lane, bn, scx, scy, shx, shy);
          for (int base = sBc + 64; base < eBc; base += 64){
            int rem = eBc - base; if (rem > 64) rem = 64;
            int vidx = 0;
            if (base + lane < eBc) vidx = csr[base + lane];
            acc_chunk(vx, vy, ux, uy, vidx, rem, tab, lane, bn, scx, scy, shx, shy);
          }
          float inv = 1.f / (float)(n > 1 ? n : 1);
          vx = (vx + ux) * inv;
          vy = (vy + uy) * inv;
        }
        uint32 pk = ((uint32)f2bf(vy) << 16) | (uint32)f2bf(vx);
        *(uint32*)&As[r][part*128 + 2*lane] = pk;
      }
      vA = vNA; vB = vNB;
    }
  }

  // ---- self part ----
  {
    const bool bn = (A.scd != nullptr);
    float scx = 1.f, scy = 1.f, shx = 0.f, shy = 0.f;
    if (bn){
      scx = A.scd[2*lane]; scy = A.scd[2*lane+1];
      shx = A.shd[2*lane]; shy = A.shd[2*lane+1];
    }
    for (int rr = 0; rr < 8; ++rr){
      int r = (wave << 3) + rr;
      int row = row0 + r;
      float vx = 0.f, vy = 0.f;
      if (row < M){
        uint32 x = *(const uint32*)(A.tabd + (size_t)row*FH + 2*lane);
        float fx = bfl(x), fy = bfh(x);
        if (bn){
          vx = lrelu(fmaf(fx, scx, shx));
          vy = lrelu(fmaf(fy, scy, shy));
        } else { vx = fx; vy = fy; }
      }
      uint32 pk = ((uint32)f2bf(vy) << 16) | (uint32)f2bf(vx);
      *(uint32*)&As[r][256 + 2*lane] = pk;
    }
  }
  __syncthreads();

  // ---- MFMA: wave = 16 rows x 64 cols; K = 384 ----
  const int rowtile = wave >> 1;
  const int colhalf = wave & 1;
  const int qm  = lane & 15;
  const int quad = lane >> 4;
  f32x4 acc[4] = {{0,0,0,0},{0,0,0,0},{0,0,0,0},{0,0,0,0}};
  const u16* abase = &As[rowtile*16 + qm][quad*8];
  const u16* wbase = A.Wt + ((size_t)(colhalf*64 + qm) * 384 + quad*8);

  #pragma unroll
  for (int k0 = 0; k0 < 384; k0 += 32){
    bf16x8 a  = *(const bf16x8*)(abase + k0);
    bf16x8 b0 = *(const bf16x8*)(wbase + 0*16*384 + k0);
    bf16x8 b1 = *(const bf16x8*)(wbase + 1*16*384 + k0);
    bf16x8 b2 = *(const bf16x8*)(wbase + 2*16*384 + k0);
    bf16x8 b3 = *(const bf16x8*)(wbase + 3*16*384 + k0);
    acc[0] = __builtin_amdgcn_mfma_f32_16x16x32_bf16(a, b0, acc[0], 0, 0, 0);
    acc[1] = __builtin_amdgcn_mfma_f32_16x16x32_bf16(a, b1, acc[1], 0, 0, 0);
    acc[2] = __builtin_amdgcn_mfma_f32_16x16x32_bf16(a, b2, acc[2], 0, 0, 0);
    acc[3] = __builtin_amdgcn_mfma_f32_16x16x32_bf16(a, b3, acc[3], 0, 0, 0);
  }

  // ---- epilogue + per-thread BN partial sums ----
  float sl[4], ql[4];
  #pragma unroll
  for (int f = 0; f < 4; ++f){
    sl[f] = 0.f; ql[f] = 0.f;
    int col = colhalf*64 + f*16 + qm;
    float bi = A.bias[col];
    #pragma unroll
    for (int reg = 0; reg < 4; ++reg){
      int row = row0 + rowtile*16 + quad*4 + reg;
      if (row < M){
        float o = acc[f][reg] + bi;
        if (A.out32) A.out32[(size_t)row*FH + col] = o;
        if (A.out16) A.out16[(size_t)row*FH + col] = f2bf(o);
        sl[f] += o; ql[f] += o*o;
      }
    }
  }

  // ---- fused BN stats: LDS reduce (reuse As) + one atomic per col per block ----
  __syncthreads();                       // all MFMA A-reads done; safe to reuse As
  float* S = (float*)As;                 // [128][8]
  float* Q = S + 1024;                   // [128][8]
  int slot = rowtile*4 + quad;
  #pragma unroll
  for (int f = 0; f < 4; ++f){
    int col = colhalf*64 + f*16 + qm;
    S[col*8 + slot] = sl[f];
    Q[col*8 + slot] = ql[f];
  }
  __syncthreads();
  if (tid < 128){
    float s = 0.f;
    #pragma unroll
    for (int k = 0; k < 8; ++k) s += S[tid*8 + k];
    atomicAdd(A.gsum + tid, s);
  } else {
    int c = tid - 128;
    float q = 0.f;
    #pragma unroll
    for (int k = 0; k < 8; ++k) q += Q[c*8 + k];
    atomicAdd(A.gsq + c, q);
  }
}

// host blocks first (denser rows start early), flow blocks fill behind
__global__ __launch_bounds__(256, 6) void k_gemm2(GemmArgs H, GemmArgs F, int gH){
  __shared__ u16 As[32][392];
  if ((int)blockIdx.x < gH) gemm_body(H, blockIdx.x, As);
  else                      gemm_body(F, blockIdx.x - gH, As);
}

// ---------------- BN finalize / apply ----------------
__global__ void k_bn_finalize(const float* __restrict__ sF, const float* __restrict__ qF, float invMF,
                              const float* __restrict__ sH, const float* __restrict__ qH, float invMH,
                              const float* __restrict__ gamma, const float* __restrict__ beta,
                              float* scF, float* shF, float* scH, float* shH){
  int t = threadIdx.x;
  if (t < 128){
    float mu = sF[t] * invMF;
    float var = qF[t] * invMF - mu*mu;
    float s = gamma[t] * rsqrtf(var + BNEPS);
    scF[t] = s; shF[t] = beta[t] - mu*s;
  } else {
    int f = t - 128;
    float mu = sH[f] * invMH;
    float var = qH[f] * invMH - mu*mu;
    float s = gamma[f] * rsqrtf(var + BNEPS);
    scH[f] = s; shH[f] = beta[f] - mu*s;
  }
}

__global__ void k_apply2(float* __restrict__ xf, int n4F,
                         const float* __restrict__ scF, const float* __restrict__ shF,
                         float* __restrict__ xh, int n4H,
                         const float* __restrict__ scH, const float* __restrict__ shH){
  int g = blockIdx.x * blockDim.x + threadIdx.x;
  int stride = gridDim.x * blockDim.x;
  int tot = n4F + n4H;
  for (int i = g; i < tot; i += stride){
    float* x; const float* sc; const float* shf; int idx;
    if (i < n4F){ x = xf; sc = scF; shf = shF; idx = i; }
    else        { x = xh; sc = scH; shf = shH; idx = i - n4F; }
    float4 v = ((const float4*)x)[idx];
    int f = (idx*4) & 127;
    float4 s = *(const float4*)(sc + f);
    float4 b = *(const float4*)(shf + f);
    v.x = lrelu(fmaf(v.x, s.x, b.x));
    v.y = lrelu(fmaf(v.y, s.y, b.y));
    v.z = lrelu(fmaf(v.z, s.z, b.z));
    v.w = lrelu(fmaf(v.w, s.w, b.w));
    ((float4*)x)[idx] = v;
  }
}

// ---------------- launch ----------------
extern "C" void kernel_launch(void* const* d_in, const int* in_sizes, int n_in,
                              void* d_out, int out_size, void* d_ws, size_t ws_size,
                              hipStream_t stream) {
  const float* x_host = (const float*)d_in[0];
  const float* x_flow = (const float*)d_in[1];
  const int* ei_s  = (const int*)d_in[2];
  const int* ei_rv = (const int*)d_in[3];
  const int* ei_p  = (const int*)d_in[4];
  const int* ei_rc = (const int*)d_in[5];
  const float* Wl    = (const float*)d_in[6];
  const float* bl    = (const float*)d_in[7];
  const float* Wr    = (const float*)d_in[8];
  const float* gamma = (const float*)d_in[9];
  const float* beta  = (const float*)d_in[10];

  const int NH = in_sizes[0] / FH;   // 50000
  const int NF = in_sizes[1] / FH;   // 200000
  const int Es  = in_sizes[2] / 2;
  const int Erv = in_sizes[3] / 2;
  const int Ep  = in_sizes[4] / 2;
  const int Erc = in_sizes[5] / 2;

  float* out_h = (float*)d_out;
  float* out_f = (float*)d_out + (size_t)NH * FH;

  char* p = (char*)d_ws;
  auto alloc = [&](size_t bytes) -> void* {
    void* r = (void*)p;
    p += (bytes + 255) & ~(size_t)255;
    return r;
  };
  u16* xf16  = (u16*)alloc((size_t)NF * FH * 2);  // bf16 input tables
  u16* xh16  = (u16*)alloc((size_t)NH * FH * 2);
  u16* f16_0 = (u16*)alloc((size_t)NF * FH * 2);  // block-0 raw outputs (bf16)
  u16* h16_0 = (u16*)alloc((size_t)NH * FH * 2);
  u16* wcat  = (u16*)alloc((size_t)4 * 49152 * 2); // bf16 Wt[which][c][k]
  float* bcat   = (float*)alloc(512 * 4);
  float* stats  = (float*)alloc(1024 * 4);
  float* ssbuf  = (float*)alloc(1024 * 4);
  int* cnt_s = (int*)alloc((size_t)NF * 4);
  int* cnt_p = (int*)alloc((size_t)NF * 4);
  int* cnt_r = (int*)alloc((size_t)NH * 4);
  int* cnt_q = (int*)alloc((size_t)NH * 4);
  int* off_s = (int*)alloc((size_t)(NF+1) * 4);
  int* off_p = (int*)alloc((size_t)(NF+1) * 4);
  int* off_r = (int*)alloc((size_t)(NH+1) * 4);
  int* off_q = (int*)alloc((size_t)(NH+1) * 4);
  int* cur_s = (int*)alloc((size_t)NF * 4);
  int* cur_p = (int*)alloc((size_t)NF * 4);
  int* cur_r = (int*)alloc((size_t)NH * 4);
  int* cur_q = (int*)alloc((size_t)NH * 4);
  int* csr_s = (int*)alloc((size_t)Es * 4);
  int* csr_p = (int*)alloc((size_t)Ep * 4);
  int* csr_r = (int*)alloc((size_t)Erv * 4);
  int* csr_q = (int*)alloc((size_t)Erc * 4);
  int* ssum  = (int*)alloc(1024 * 4);

  size_t cnt_bytes = (char*)cnt_q + (size_t)NH*4 - (char*)cnt_s;
  hipMemsetAsync(cnt_s, 0, cnt_bytes, stream);
  hipMemsetAsync(stats, 0, 1024 * 4, stream);

  k_prep<<<(4*128*384 + 512 + 255)/256, 256, 0, stream>>>(Wl, bl, Wr, wcat, bcat);
  k_cvt2<<<2048, 256, 0, stream>>>(x_flow, xf16, NF * FH / 4, x_host, xh16, NH * FH / 4);

  int maxE = Ep;  // largest edge list
  dim3 ghist((maxE + 255)/256, 4);
  k_hist4<<<ghist, 256, 0, stream>>>(ei_s + Es, Es, ei_p + Ep, Ep,
                                     ei_rv + Erv, Erv, ei_rc + Erc, Erc,
                                     cnt_s, cnt_p, cnt_r, cnt_q);

  int nchF = (NF + 1023) / 1024;   // 196
  int nchH = (NH + 1023) / 1024;   // 49
  dim3 gscan(nchF, 4);
  k_chunk_sums<<<gscan, 256, 0, stream>>>(cnt_s, cnt_p, cnt_r, cnt_q, NF, NF, NH, NH, ssum);
  k_scan_sums<<<4, 256, 0, stream>>>(ssum, nchF, nchF, nchH, nchH);
  k_write_offsets<<<gscan, 256, 0, stream>>>(cnt_s, cnt_p, cnt_r, cnt_q,
                                             off_s, off_p, off_r, off_q,
                                             cur_s, cur_p, cur_r, cur_q,
                                             NF, NF, NH, NH, ssum);

  k_fill4<<<ghist, 256, 0, stream>>>(ei_s, ei_s + Es, Es,  ei_p, ei_p + Ep, Ep,
                                     ei_rv, ei_rv + Erv, Erv,  ei_rc, ei_rc + Erc, Erc,
                                     cur_s, cur_p, cur_r, cur_q,
                                     csr_s, csr_p, csr_r, csr_q);

  int gF = (NF + 31) / 32;   // 6250
  int gH = (NH + 31) / 32;   // 1563

  for (int blk = 0; blk < 2; ++blk){
    const u16* fcur = blk ? f16_0 : xf16;
    const u16* hcur = blk ? h16_0 : xh16;
    const float* scF = blk ? ssbuf + 0   : nullptr;
    const float* shF = blk ? ssbuf + 128 : nullptr;
    const float* scH = blk ? ssbuf + 256 : nullptr;
    const float* shH = blk ? ssbuf + 384 : nullptr;
    float* st = stats + blk * 512;

    GemmArgs F;
    F.M = NF;
    F.off0 = off_s; F.csr0 = csr_s; F.tab0 = hcur; F.sc0 = scH; F.sh0 = shH;
    F.off1 = off_p; F.csr1 = csr_p; F.tab1 = fcur; F.sc1 = scF; F.sh1 = shF;
    F.tabd = fcur; F.scd = scF; F.shd = shF;
    F.Wt = wcat + (size_t)(blk*2 + 0) * 49152;
    F.bias = bcat + (blk*2 + 0) * 128;
    F.out32 = blk ? out_f : nullptr;
    F.out16 = blk ? nullptr : f16_0;
    F.gsum = st + 0; F.gsq = st + 128;

    GemmArgs H;
    H.M = NH;
    H.off0 = off_r; H.csr0 = csr_r; H.tab0 = fcur; H.sc0 = scF; H.sh0 = shF;
    H.off1 = off_q; H.csr1 = csr_q; H.tab1 = fcur; H.sc1 = scF; H.sh1 = shF;
    H.tabd = hcur; H.scd = scH; H.shd = shH;
    H.Wt = wcat + (size_t)(blk*2 + 1) * 49152;
    H.bias = bcat + (blk*2 + 1) * 128;
    H.out32 = blk ? out_h : nullptr;
    H.out16 = blk ? nullptr : h16_0;
    H.gsum = st + 256; H.gsq = st + 384;

    k_gemm2<<<gH + gF, 256, 0, stream>>>(H, F, gH);

    float* ss = ssbuf + blk * 512;
    k_bn_finalize<<<1, 256, 0, stream>>>(st + 0, st + 128, 1.f/(float)NF,
                                         st + 256, st + 384, 1.f/(float)NH,
                                         gamma + blk*128, beta + blk*128,
                                         ss + 0, ss + 128, ss + 256, ss + 384);
  }

  k_apply2<<<2048, 256, 0, stream>>>(out_f, NF * FH / 4, ssbuf + 512 + 0,   ssbuf + 512 + 128,
                                     out_h, NH * FH / 4, ssbuf + 512 + 256, ssbuf + 512 + 384);
}

// Round 8
// 1194.883 us; speedup vs baseline: 1.6568x; 1.3939x over previous
//
#include <hip/hip_runtime.h>

#define FH 128
#define NEG 0.01f
#define BNEPS 1e-5f
#define NB 256
#define EPB 8192

typedef unsigned int uint32;
typedef unsigned short u16;
typedef __attribute__((ext_vector_type(8))) short bf16x8;
typedef __attribute__((ext_vector_type(4))) float f32x4;

__device__ __forceinline__ float lrelu(float v){ return v >= 0.f ? v : NEG * v; }
__device__ __forceinline__ float bfl(uint32 u){ return __uint_as_float(u << 16); }
__device__ __forceinline__ float bfh(uint32 u){ return __uint_as_float(u & 0xffff0000u); }
__device__ __forceinline__ u16 f2bf(float f){
  uint32 u = __float_as_uint(f);
  u += 0x7fffu + ((u >> 16) & 1u);   // RNE
  return (u16)(u >> 16);
}

// ---------------- fp32 -> bf16 table conversion (both tables, one launch) ----------
__global__ void k_cvt2(const float* __restrict__ xf, u16* __restrict__ tf, int n4F,
                       const float* __restrict__ xh, u16* __restrict__ th, int n4H){
  int g = blockIdx.x * 256 + threadIdx.x;
  int stride = gridDim.x * 256;
  int tot = n4F + n4H;
  for (int i = g; i < tot; i += stride){
    const float4* src; ushort4* dst; int idx;
    if (i < n4F){ src = (const float4*)xf; dst = (ushort4*)tf; idx = i; }
    else        { src = (const float4*)xh; dst = (ushort4*)th; idx = i - n4F; }
    float4 v = src[idx];
    ushort4 p;
    p.x = f2bf(v.x); p.y = f2bf(v.y); p.z = f2bf(v.z); p.w = f2bf(v.w);
    dst[idx] = p;
  }
}

// ================= deterministic bucket CSR build =================
// type order a: 0=sends(->NF), 1=precedes(->NF), 2=rev(->NH), 3=reaches(->NH)

// A: per-block 256-bucket LDS histogram -> M[a][bx][b]  (no global atomics)
__global__ void k_bcount(const int* d0,int E0, const int* d1,int E1,
                         const int* d2,int E2, const int* d3,int E3,
                         int sh0,int sh1,int sh2,int sh3, int* __restrict__ M){
  int a = blockIdx.y;
  const int* dst = a==0?d0 : a==1?d1 : a==2?d2 : d3;
  int E  = a==0?E0 : a==1?E1 : a==2?E2 : E3;
  int sh = a==0?sh0: a==1?sh1: a==2?sh2: sh3;
  int bx = blockIdx.x;
  int base = bx * EPB;
  if (base >= E) return;
  __shared__ int h[NB];
  h[threadIdx.x] = 0;
  __syncthreads();
  int end = base + EPB; if (end > E) end = E;
  for (int i = base + threadIdx.x; i < end; i += 256)
    atomicAdd(&h[dst[i] >> sh], 1);
  __syncthreads();
  M[(a*NB + bx)*NB + threadIdx.x] = h[threadIdx.x];
}

// B1: per-bucket exclusive scan over blocks; bucket totals -> T
__global__ void k_bscanA(int n0,int n1,int n2,int n3, int* __restrict__ M, int* __restrict__ T){
  int a = blockIdx.y, b = blockIdx.x, t = threadIdx.x;
  int nbx = a==0?n0 : a==1?n1 : a==2?n2 : n3;   // <= 256 (E <= 2.09M per type)
  __shared__ int shm[256];
  int v = (t < nbx) ? M[(a*NB + t)*NB + b] : 0;
  shm[t] = v; __syncthreads();
  for (int o = 1; o < 256; o <<= 1){
    int x = shm[t];
    if (t >= o) x += shm[t-o];
    __syncthreads();
    shm[t] = x;
    __syncthreads();
  }
  if (t < nbx) M[(a*NB + t)*NB + b] = shm[t] - v;
  if (t == 255) T[a*NB + b] = shm[255];
}

// B2: exclusive scan over bucket totals -> Bb (257 entries per type; Bb[256]=E)
__global__ void k_bscanB(const int* __restrict__ T, int* __restrict__ Bb){
  int a = blockIdx.x, t = threadIdx.x;
  __shared__ int shm[256];
  int v = T[a*NB + t];
  shm[t] = v; __syncthreads();
  for (int o = 1; o < 256; o <<= 1){
    int x = shm[t];
    if (t >= o) x += shm[t-o];
    __syncthreads();
    shm[t] = x;
    __syncthreads();
  }
  Bb[a*257 + t] = shm[t] - v;
  if (t == 255) Bb[a*257 + 256] = shm[255];
}

// C: deterministic bucket append of (src,dst) pairs into scratch (LDS cursors only)
__global__ void k_bappend(const int* s0_,const int* d0,int E0, const int* s1_,const int* d1,int E1,
                          const int* s2_,const int* d2,int E2, const int* s3_,const int* d3,int E3,
                          int sh0,int sh1,int sh2,int sh3,
                          const int* __restrict__ M, const int* __restrict__ Bb,
                          uint2* r0, uint2* r1, uint2* r2, uint2* r3){
  int a = blockIdx.y;
  const int* src = a==0?s0_ : a==1?s1_ : a==2?s2_ : s3_;
  const int* dst = a==0?d0 : a==1?d1 : a==2?d2 : d3;
  int E  = a==0?E0 : a==1?E1 : a==2?E2 : E3;
  int sh = a==0?sh0: a==1?sh1: a==2?sh2: sh3;
  uint2* scr = a==0?r0 : a==1?r1 : a==2?r2 : r3;
  int bx = blockIdx.x;
  int base = bx * EPB;
  if (base >= E) return;
  __shared__ int cur[NB];
  cur[threadIdx.x] = Bb[a*257 + threadIdx.x] + M[(a*NB + bx)*NB + threadIdx.x];
  __syncthreads();
  int end = base + EPB; if (end > E) end = E;
  for (int i = base + threadIdx.x; i < end; i += 256){
    int d = dst[i];
    int slot = atomicAdd(&cur[d >> sh], 1);
    uint2 pr; pr.x = (uint32)src[i]; pr.y = (uint32)d;
    scr[slot] = pr;
  }
}

// D1: per bucket: LDS dst-histogram + LDS scan -> write off[] directly
// (bucket scratch base == global edge offset since buckets partition dst space)
__global__ void k_doff(const uint2* r0,const uint2* r1,const uint2* r2,const uint2* r3,
                       int sh0,int sh1,int sh2,int sh3, int N0,int N1,int N2,int N3,
                       const int* __restrict__ Bb,
                       int* o0,int* o1,int* o2,int* o3){
  int a = blockIdx.y, b = blockIdx.x, t = threadIdx.x;
  const uint2* scr = a==0?r0 : a==1?r1 : a==2?r2 : r3;
  int sh = a==0?sh0: a==1?sh1: a==2?sh2: sh3;
  int N  = a==0?N0 : a==1?N1 : a==2?N2 : N3;
  int* off = a==0?o0 : a==1?o1 : a==2?o2 : o3;
  int lo = b << sh;
  if (lo >= N) return;
  int span = (1 << sh); if (lo + span > N) span = N - lo;
  __shared__ int cnt[1024];
  #pragma unroll
  for (int k = 0; k < 4; ++k) cnt[t*4 + k] = 0;
  __syncthreads();
  int e0 = Bb[a*257 + b], e1 = Bb[a*257 + b + 1];
  for (int e = e0 + t; e < e1; e += 256)
    atomicAdd(&cnt[(int)scr[e].y - lo], 1);
  __syncthreads();
  int c[4]; int ts = 0;
  #pragma unroll
  for (int k = 0; k < 4; ++k){ c[k] = cnt[t*4 + k]; ts += c[k]; }
  __shared__ int ws2[256];
  ws2[t] = ts; __syncthreads();
  for (int o = 1; o < 256; o <<= 1){
    int x = ws2[t];
    if (t >= o) x += ws2[t-o];
    __syncthreads();
    ws2[t] = x;
    __syncthreads();
  }
  int run = e0 + ws2[t] - ts;
  #pragma unroll
  for (int k = 0; k < 4; ++k){
    int j = t*4 + k;
    if (j < span) off[lo + j] = run;
    run += c[k];
  }
  if (t == 255 && lo + span == N) off[N] = e1;   // last active bucket closes off[]
}

// D2: per bucket: LDS cursors from off[], place src into csr (L2-local writes)
__global__ void k_place(const uint2* r0,const uint2* r1,const uint2* r2,const uint2* r3,
                        int sh0,int sh1,int sh2,int sh3, int N0,int N1,int N2,int N3,
                        const int* __restrict__ Bb,
                        const int* o0,const int* o1,const int* o2,const int* o3,
                        int* c0,int* c1,int* c2,int* c3){
  int a = blockIdx.y, b = blockIdx.x, t = threadIdx.x;
  const uint2* scr = a==0?r0 : a==1?r1 : a==2?r2 : r3;
  int sh = a==0?sh0: a==1?sh1: a==2?sh2: sh3;
  int N  = a==0?N0 : a==1?N1 : a==2?N2 : N3;
  const int* off = a==0?o0 : a==1?o1 : a==2?o2 : o3;
  int* csr = a==0?c0 : a==1?c1 : a==2?c2 : c3;
  int lo = b << sh;
  if (lo >= N) return;
  int span = (1 << sh); if (lo + span > N) span = N - lo;
  __shared__ int cur[1024];
  #pragma unroll
  for (int k = 0; k < 4; ++k){
    int j = t*4 + k;
    cur[j] = (j < span) ? off[lo + j] : 0;
  }
  __syncthreads();
  int e0 = Bb[a*257 + b], e1 = Bb[a*257 + b + 1];
  for (int e = e0 + t; e < e1; e += 256){
    uint2 pr = scr[e];
    int slot = atomicAdd(&cur[(int)pr.y - lo], 1);
    csr[slot] = (int)pr.x;
  }
}

// ---------------- weight concat (bf16, transposed: Wt[which][c][k]) ----------------
__global__ void k_prep(const float* __restrict__ Wl, const float* __restrict__ bl,
                       const float* __restrict__ Wr, u16* __restrict__ wt,
                       float* __restrict__ bcat){
  int g = blockIdx.x * 256 + threadIdx.x;
  const int NW = 4 * 128 * 384;
  if (g < NW){
    int which = g / 49152;          // blk*2 + side
    int blk = which >> 1, side = which & 1;
    int idx = g % 49152;
    int c = idx / 384;              // out col 0..127
    int k = idx % 384;              // 0..383
    int part = k >> 7, kk = k & 127;
    int tA = side == 0 ? 0 : 1;
    int tB = side == 0 ? 2 : 3;
    float v;
    if (part == 0)      v = 0.5f * Wl[(((blk*4 + tA)*128 + c)*128) + kk];
    else if (part == 1) v = 0.5f * Wl[(((blk*4 + tB)*128 + c)*128) + kk];
    else v = 0.5f * (Wr[(((blk*4 + tA)*128 + c)*128) + kk] + Wr[(((blk*4 + tB)*128 + c)*128) + kk]);
    wt[g] = f2bf(v);
  } else if (g < NW + 512){
    int i = g - NW;
    int which = i >> 7;
    int blk = which >> 1, side = which & 1;
    int c = i & 127;
    int tA = side == 0 ? 0 : 1;
    int tB = side == 0 ? 2 : 3;
    bcat[which*128 + c] = 0.5f * (bl[(blk*4 + tA)*128 + c] + bl[(blk*4 + tB)*128 + c]);
  }
}

// ---- edge-chunk accumulate: EXACT round-5 summation order (vx even / ux odd) ----
__device__ __forceinline__ void acc_chunk(
    float& vx, float& vy, float& ux, float& uy,
    int vidx, int rem, const u16* __restrict__ tab, int lane, bool bn,
    float scx, float scy, float shx, float shy)
{
  int i = 0;
  if (bn){
    for (; i + 8 <= rem; i += 8){
      int t0 = __shfl(vidx, i),   t1 = __shfl(vidx, i+1);
      int t2 = __shfl(vidx, i+2), t3 = __shfl(vidx, i+3);
      int t4 = __shfl(vidx, i+4), t5 = __shfl(vidx, i+5);
      int t6 = __shfl(vidx, i+6), t7 = __shfl(vidx, i+7);
      uint32 x0 = *(const uint32*)(tab + (size_t)t0*FH + 2*lane);
      uint32 x1 = *(const uint32*)(tab + (size_t)t1*FH + 2*lane);
      uint32 x2 = *(const uint32*)(tab + (size_t)t2*FH + 2*lane);
      uint32 x3 = *(const uint32*)(tab + (size_t)t3*FH + 2*lane);
      uint32 x4 = *(const uint32*)(tab + (size_t)t4*FH + 2*lane);
      uint32 x5 = *(const uint32*)(tab + (size_t)t5*FH + 2*lane);
      uint32 x6 = *(const uint32*)(tab + (size_t)t6*FH + 2*lane);
      uint32 x7 = *(const uint32*)(tab + (size_t)t7*FH + 2*lane);
      vx += lrelu(fmaf(bfl(x0), scx, shx)); vy += lrelu(fmaf(bfh(x0), scy, shy));
      ux += lrelu(fmaf(bfl(x1), scx, shx)); uy += lrelu(fmaf(bfh(x1), scy, shy));
      vx += lrelu(fmaf(bfl(x2), scx, shx)); vy += lrelu(fmaf(bfh(x2), scy, shy));
      ux += lrelu(fmaf(bfl(x3), scx, shx)); uy += lrelu(fmaf(bfh(x3), scy, shy));
      vx += lrelu(fmaf(bfl(x4), scx, shx)); vy += lrelu(fmaf(bfh(x4), scy, shy));
      ux += lrelu(fmaf(bfl(x5), scx, shx)); uy += lrelu(fmaf(bfh(x5), scy, shy));
      vx += lrelu(fmaf(bfl(x6), scx, shx)); vy += lrelu(fmaf(bfh(x6), scy, shy));
      ux += lrelu(fmaf(bfl(x7), scx, shx)); uy += lrelu(fmaf(bfh(x7), scy, shy));
    }
    for (; i + 4 <= rem; i += 4){
      int s0 = __shfl(vidx, i),   s1 = __shfl(vidx, i+1);
      int s2 = __shfl(vidx, i+2), s3 = __shfl(vidx, i+3);
      uint32 x0 = *(const uint32*)(tab + (size_t)s0*FH + 2*lane);
      uint32 x1 = *(const uint32*)(tab + (size_t)s1*FH + 2*lane);
      uint32 x2 = *(const uint32*)(tab + (size_t)s2*FH + 2*lane);
      uint32 x3 = *(const uint32*)(tab + (size_t)s3*FH + 2*lane);
      vx += lrelu(fmaf(bfl(x0), scx, shx)); vy += lrelu(fmaf(bfh(x0), scy, shy));
      ux += lrelu(fmaf(bfl(x1), scx, shx)); uy += lrelu(fmaf(bfh(x1), scy, shy));
      vx += lrelu(fmaf(bfl(x2), scx, shx)); vy += lrelu(fmaf(bfh(x2), scy, shy));
      ux += lrelu(fmaf(bfl(x3), scx, shx)); uy += lrelu(fmaf(bfh(x3), scy, shy));
    }
    for (; i < rem; ++i){
      int s0 = __shfl(vidx, i);
      uint32 x0 = *(const uint32*)(tab + (size_t)s0*FH + 2*lane);
      vx += lrelu(fmaf(bfl(x0), scx, shx)); vy += lrelu(fmaf(bfh(x0), scy, shy));
    }
  } else {
    for (; i + 8 <= rem; i += 8){
      int t0 = __shfl(vidx, i),   t1 = __shfl(vidx, i+1);
      int t2 = __shfl(vidx, i+2), t3 = __shfl(vidx, i+3);
      int t4 = __shfl(vidx, i+4), t5 = __shfl(vidx, i+5);
      int t6 = __shfl(vidx, i+6), t7 = __shfl(vidx, i+7);
      uint32 x0 = *(const uint32*)(tab + (size_t)t0*FH + 2*lane);
      uint32 x1 = *(const uint32*)(tab + (size_t)t1*FH + 2*lane);
      uint32 x2 = *(const uint32*)(tab + (size_t)t2*FH + 2*lane);
      uint32 x3 = *(const uint32*)(tab + (size_t)t3*FH + 2*lane);
      uint32 x4 = *(const uint32*)(tab + (size_t)t4*FH + 2*lane);
      uint32 x5 = *(const uint32*)(tab + (size_t)t5*FH + 2*lane);
      uint32 x6 = *(const uint32*)(tab + (size_t)t6*FH + 2*lane);
      uint32 x7 = *(const uint32*)(tab + (size_t)t7*FH + 2*lane);
      vx += bfl(x0); vy += bfh(x0);
      ux += bfl(x1); uy += bfh(x1);
      vx += bfl(x2); vy += bfh(x2);
      ux += bfl(x3); uy += bfh(x3);
      vx += bfl(x4); vy += bfh(x4);
      ux += bfl(x5); uy += bfh(x5);
      vx += bfl(x6); vy += bfh(x6);
      ux += bfl(x7); uy += bfh(x7);
    }
    for (; i + 4 <= rem; i += 4){
      int s0 = __shfl(vidx, i),   s1 = __shfl(vidx, i+1);
      int s2 = __shfl(vidx, i+2), s3 = __shfl(vidx, i+3);
      uint32 x0 = *(const uint32*)(tab + (size_t)s0*FH + 2*lane);
      uint32 x1 = *(const uint32*)(tab + (size_t)s1*FH + 2*lane);
      uint32 x2 = *(const uint32*)(tab + (size_t)s2*FH + 2*lane);
      uint32 x3 = *(const uint32*)(tab + (size_t)s3*FH + 2*lane);
      vx += bfl(x0); vy += bfh(x0);
      ux += bfl(x1); uy += bfh(x1);
      vx += bfl(x2); vy += bfh(x2);
      ux += bfl(x3); uy += bfh(x3);
    }
    for (; i < rem; ++i){
      int s0 = __shfl(vidx, i);
      uint32 x0 = *(const uint32*)(tab + (size_t)s0*FH + 2*lane);
      vx += bfl(x0); vy += bfh(x0);
    }
  }
}

// ---------------- merged gather+GEMM args ----------------
struct GemmArgs {
  int M;
  const int* off0; const int* csr0; const u16* tab0; const float* sc0; const float* sh0;
  const int* off1; const int* csr1; const u16* tab1; const float* sc1; const float* sh1;
  const u16* tabd; const float* scd; const float* shd;
  const u16* Wt; const float* bias;
  float* out32; u16* out16;
  float* gsum; float* gsq;     // fused BN stats accumulators (128 floats each)
};

// Round-5 gather + MFMA body, plus fused BN-stats epilogue.
__device__ __forceinline__ void gemm_body(const GemmArgs& A, int bx, u16 (*As)[392]){
  const int M = A.M;
  const int tid = threadIdx.x;
  const int row0 = bx * 32;
  const int lane = tid & 63;
  const int wave = tid >> 6;
  const int rbase = row0 + (wave << 3);

  for (int part = 0; part < 2; ++part){
    const int* off = part ? A.off1 : A.off0;
    const int* csr = part ? A.csr1 : A.csr0;
    const u16* tab = part ? A.tab1 : A.tab0;
    const float* sc = part ? A.sc1 : A.sc0;
    const float* sh = part ? A.sh1 : A.sh0;
    const bool bn = (sc != nullptr);
    float scx = 1.f, scy = 1.f, shx = 0.f, shy = 0.f;
    if (bn){
      scx = sc[2*lane]; scy = sc[2*lane+1];
      shx = sh[2*lane]; shy = sh[2*lane+1];
    }

    int oidx = rbase + lane;
    int offv = 0;
    if (lane < 9) offv = off[oidx <= M ? oidx : M];

    int sA = __shfl(offv, 0), eA = __shfl(offv, 1);
    int sB = eA,              eB = __shfl(offv, 2);
    int vA = 0, vB = 0;
    if (sA + lane < eA) vA = csr[sA + lane];
    if (sB + lane < eB) vB = csr[sB + lane];

    for (int g = 0; g < 4; ++g){
      int rA = 2*g, rB = 2*g + 1;
      int sAc = __shfl(offv, rA), eAc = __shfl(offv, rA+1);
      int sBc = eAc,              eBc = __shfl(offv, rB+1);

      int vNA = 0, vNB = 0;
      if (g < 3){
        int sNA = __shfl(offv, rA+2), eNA = __shfl(offv, rA+3);
        int sNB = eNA,                eNB = __shfl(offv, rA+4);
        if (sNA + lane < eNA) vNA = csr[sNA + lane];
        if (sNB + lane < eNB) vNB = csr[sNB + lane];
      }

      {
        int r = (wave << 3) + rA;
        int row = row0 + r;
        float vx = 0.f, vy = 0.f;
        if (row < M){
          int n = eAc - sAc;
          float ux = 0.f, uy = 0.f;
          int rem0 = n > 64 ? 64 : n;
          acc_chunk(vx, vy, ux, uy, vA, rem0, tab, lane, bn, scx, scy, shx, shy);
          for (int base = sAc + 64; base < eAc; base += 64){
            int rem = eAc - base; if (rem > 64) rem = 64;
            int vidx = 0;
            if (base + lane < eAc) vidx = csr[base + lane];
            acc_chunk(vx, vy, ux, uy, vidx, rem, tab, lane, bn, scx, scy, shx, shy);
          }
          float inv = 1.f / (float)(n > 1 ? n : 1);
          vx = (vx + ux) * inv;
          vy = (vy + uy) * inv;
        }
        uint32 pk = ((uint32)f2bf(vy) << 16) | (uint32)f2bf(vx);
        *(uint32*)&As[r][part*128 + 2*lane] = pk;
      }
      {
        int r = (wave << 3) + rB;
        int row = row0 + r;
        float vx = 0.f, vy = 0.f;
        if (row < M){
          int n = eBc - sBc;
          float ux = 0.f, uy = 0.f;
          int rem0 = n > 64 ? 64 : n;
          acc_chunk(vx, vy, ux, uy, vB, rem0, tab, lane, bn, scx, scy, shx, shy);
          for (int base = sBc + 64; base < eBc; base += 64){
            int rem = eBc - base; if (rem > 64) rem = 64;
            int vidx = 0;
            if (base + lane < eBc) vidx = csr[base + lane];
            acc_chunk(vx, vy, ux, uy, vidx, rem, tab, lane, bn, scx, scy, shx, shy);
          }
          float inv = 1.f / (float)(n > 1 ? n : 1);
          vx = (vx + ux) * inv;
          vy = (vy + uy) * inv;
        }
        uint32 pk = ((uint32)f2bf(vy) << 16) | (uint32)f2bf(vx);
        *(uint32*)&As[r][part*128 + 2*lane] = pk;
      }
      vA = vNA; vB = vNB;
    }
  }

  // ---- self part ----
  {
    const bool bn = (A.scd != nullptr);
    float scx = 1.f, scy = 1.f, shx = 0.f, shy = 0.f;
    if (bn){
      scx = A.scd[2*lane]; scy = A.scd[2*lane+1];
      shx = A.shd[2*lane]; shy = A.shd[2*lane+1];
    }
    for (int rr = 0; rr < 8; ++rr){
      int r = (wave << 3) + rr;
      int row = row0 + r;
      float vx = 0.f, vy = 0.f;
      if (row < M){
        uint32 x = *(const uint32*)(A.tabd + (size_t)row*FH + 2*lane);
        float fx = bfl(x), fy = bfh(x);
        if (bn){
          vx = lrelu(fmaf(fx, scx, shx));
          vy = lrelu(fmaf(fy, scy, shy));
        } else { vx = fx; vy = fy; }
      }
      uint32 pk = ((uint32)f2bf(vy) << 16) | (uint32)f2bf(vx);
      *(uint32*)&As[r][256 + 2*lane] = pk;
    }
  }
  __syncthreads();

  // ---- MFMA: wave = 16 rows x 64 cols; K = 384 ----
  const int rowtile = wave >> 1;
  const int colhalf = wave & 1;
  const int qm  = lane & 15;
  const int quad = lane >> 4;
  f32x4 acc[4] = {{0,0,0,0},{0,0,0,0},{0,0,0,0},{0,0,0,0}};
  const u16* abase = &As[rowtile*16 + qm][quad*8];
  const u16* wbase = A.Wt + ((size_t)(colhalf*64 + qm) * 384 + quad*8);

  #pragma unroll
  for (int k0 = 0; k0 < 384; k0 += 32){
    bf16x8 a  = *(const bf16x8*)(abase + k0);
    bf16x8 b0 = *(const bf16x8*)(wbase + 0*16*384 + k0);
    bf16x8 b1 = *(const bf16x8*)(wbase + 1*16*384 + k0);
    bf16x8 b2 = *(const bf16x8*)(wbase + 2*16*384 + k0);
    bf16x8 b3 = *(const bf16x8*)(wbase + 3*16*384 + k0);
    acc[0] = __builtin_amdgcn_mfma_f32_16x16x32_bf16(a, b0, acc[0], 0, 0, 0);
    acc[1] = __builtin_amdgcn_mfma_f32_16x16x32_bf16(a, b1, acc[1], 0, 0, 0);
    acc[2] = __builtin_amdgcn_mfma_f32_16x16x32_bf16(a, b2, acc[2], 0, 0, 0);
    acc[3] = __builtin_amdgcn_mfma_f32_16x16x32_bf16(a, b3, acc[3], 0, 0, 0);
  }

  // ---- epilogue + per-thread BN partial sums ----
  float sl[4], ql[4];
  #pragma unroll
  for (int f = 0; f < 4; ++f){
    sl[f] = 0.f; ql[f] = 0.f;
    int col = colhalf*64 + f*16 + qm;
    float bi = A.bias[col];
    #pragma unroll
    for (int reg = 0; reg < 4; ++reg){
      int row = row0 + rowtile*16 + quad*4 + reg;
      if (row < M){
        float o = acc[f][reg] + bi;
        if (A.out32) A.out32[(size_t)row*FH + col] = o;
        if (A.out16) A.out16[(size_t)row*FH + col] = f2bf(o);
        sl[f] += o; ql[f] += o*o;
      }
    }
  }

  __syncthreads();                       // all MFMA A-reads done; safe to reuse As
  float* S = (float*)As;                 // [128][8]
  float* Q = S + 1024;                   // [128][8]
  int slot = rowtile*4 + quad;
  #pragma unroll
  for (int f = 0; f < 4; ++f){
    int col = colhalf*64 + f*16 + qm;
    S[col*8 + slot] = sl[f];
    Q[col*8 + slot] = ql[f];
  }
  __syncthreads();
  if (tid < 128){
    float s = 0.f;
    #pragma unroll
    for (int k = 0; k < 8; ++k) s += S[tid*8 + k];
    atomicAdd(A.gsum + tid, s);
  } else {
    int c = tid - 128;
    float q = 0.f;
    #pragma unroll
    for (int k = 0; k < 8; ++k) q += Q[c*8 + k];
    atomicAdd(A.gsq + c, q);
  }
}

// host blocks first (denser rows start early), flow blocks fill behind
__global__ __launch_bounds__(256, 6) void k_gemm2(GemmArgs H, GemmArgs F, int gH){
  __shared__ u16 As[32][392];
  if ((int)blockIdx.x < gH) gemm_body(H, blockIdx.x, As);
  else                      gemm_body(F, blockIdx.x - gH, As);
}

// ---------------- BN finalize / apply ----------------
__global__ void k_bn_finalize(const float* __restrict__ sF, const float* __restrict__ qF, float invMF,
                              const float* __restrict__ sH, const float* __restrict__ qH, float invMH,
                              const float* __restrict__ gamma, const float* __restrict__ beta,
                              float* scF, float* shF, float* scH, float* shH){
  int t = threadIdx.x;
  if (t < 128){
    float mu = sF[t] * invMF;
    float var = qF[t] * invMF - mu*mu;
    float s = gamma[t] * rsqrtf(var + BNEPS);
    scF[t] = s; shF[t] = beta[t] - mu*s;
  } else {
    int f = t - 128;
    float mu = sH[f] * invMH;
    float var = qH[f] * invMH - mu*mu;
    float s = gamma[f] * rsqrtf(var + BNEPS);
    scH[f] = s; shH[f] = beta[f] - mu*s;
  }
}

__global__ void k_apply2(float* __restrict__ xf, int n4F,
                         const float* __restrict__ scF, const float* __restrict__ shF,
                         float* __restrict__ xh, int n4H,
                         const float* __restrict__ scH, const float* __restrict__ shH){
  int g = blockIdx.x * blockDim.x + threadIdx.x;
  int stride = gridDim.x * blockDim.x;
  int tot = n4F + n4H;
  for (int i = g; i < tot; i += stride){
    float* x; const float* sc; const float* shf; int idx;
    if (i < n4F){ x = xf; sc = scF; shf = shF; idx = i; }
    else        { x = xh; sc = scH; shf = shH; idx = i - n4F; }
    float4 v = ((const float4*)x)[idx];
    int f = (idx*4) & 127;
    float4 s = *(const float4*)(sc + f);
    float4 b = *(const float4*)(shf + f);
    v.x = lrelu(fmaf(v.x, s.x, b.x));
    v.y = lrelu(fmaf(v.y, s.y, b.y));
    v.z = lrelu(fmaf(v.z, s.z, b.z));
    v.w = lrelu(fmaf(v.w, s.w, b.w));
    ((float4*)x)[idx] = v;
  }
}

// ---------------- launch ----------------
extern "C" void kernel_launch(void* const* d_in, const int* in_sizes, int n_in,
                              void* d_out, int out_size, void* d_ws, size_t ws_size,
                              hipStream_t stream) {
  const float* x_host = (const float*)d_in[0];
  const float* x_flow = (const float*)d_in[1];
  const int* ei_s  = (const int*)d_in[2];
  const int* ei_rv = (const int*)d_in[3];
  const int* ei_p  = (const int*)d_in[4];
  const int* ei_rc = (const int*)d_in[5];
  const float* Wl    = (const float*)d_in[6];
  const float* bl    = (const float*)d_in[7];
  const float* Wr    = (const float*)d_in[8];
  const float* gamma = (const float*)d_in[9];
  const float* beta  = (const float*)d_in[10];

  const int NH = in_sizes[0] / FH;   // 50000
  const int NF = in_sizes[1] / FH;   // 200000
  const int Es  = in_sizes[2] / 2;
  const int Erv = in_sizes[3] / 2;
  const int Ep  = in_sizes[4] / 2;
  const int Erc = in_sizes[5] / 2;

  float* out_h = (float*)d_out;
  float* out_f = (float*)d_out + (size_t)NH * FH;

  char* p = (char*)d_ws;
  auto alloc = [&](size_t bytes) -> void* {
    void* r = (void*)p;
    p += (bytes + 255) & ~(size_t)255;
    return r;
  };
  u16* xf16  = (u16*)alloc((size_t)NF * FH * 2);
  u16* xh16  = (u16*)alloc((size_t)NH * FH * 2);
  u16* f16_0 = (u16*)alloc((size_t)NF * FH * 2);
  u16* h16_0 = (u16*)alloc((size_t)NH * FH * 2);
  u16* wcat  = (u16*)alloc((size_t)4 * 49152 * 2);
  float* bcat   = (float*)alloc(512 * 4);
  float* stats  = (float*)alloc(1024 * 4);
  float* ssbuf  = (float*)alloc(1024 * 4);
  int* off_s = (int*)alloc((size_t)(NF+1) * 4);
  int* off_p = (int*)alloc((size_t)(NF+1) * 4);
  int* off_r = (int*)alloc((size_t)(NH+1) * 4);
  int* off_q = (int*)alloc((size_t)(NH+1) * 4);
  int* csr_s = (int*)alloc((size_t)Es * 4);
  int* csr_p = (int*)alloc((size_t)Ep * 4);
  int* csr_r = (int*)alloc((size_t)Erv * 4);
  int* csr_q = (int*)alloc((size_t)Erc * 4);
  uint2* scr_s = (uint2*)alloc((size_t)Es * 8);
  uint2* scr_p = (uint2*)alloc((size_t)Ep * 8);
  uint2* scr_r = (uint2*)alloc((size_t)Erv * 8);
  uint2* scr_q = (uint2*)alloc((size_t)Erc * 8);
  int* Mbuf = (int*)alloc((size_t)4 * NB * NB * 4);
  int* Tbuf = (int*)alloc((size_t)4 * NB * 4);
  int* Bbuf = (int*)alloc((size_t)4 * 257 * 4);

  hipMemsetAsync(stats, 0, 1024 * 4, stream);

  k_prep<<<(4*128*384 + 512 + 255)/256, 256, 0, stream>>>(Wl, bl, Wr, wcat, bcat);
  k_cvt2<<<2048, 256, 0, stream>>>(x_flow, xf16, NF * FH / 4, x_host, xh16, NH * FH / 4);

  // bucket shifts: smallest sh with ceil(N >> sh) <= NB
  auto mksh = [](int N){ int sh = 0; while (((N + (1 << sh) - 1) >> sh) > NB) ++sh; return sh; };
  const int shF = mksh(NF);   // 10
  const int shH = mksh(NH);   // 8

  int n_s = (Es  + EPB - 1) / EPB;
  int n_p = (Ep  + EPB - 1) / EPB;   // 245 (must stay <= NB)
  int n_r = (Erv + EPB - 1) / EPB;
  int n_q = (Erc + EPB - 1) / EPB;
  int nbxMax = n_p;
  if (n_s > nbxMax) nbxMax = n_s;
  if (n_r > nbxMax) nbxMax = n_r;
  if (n_q > nbxMax) nbxMax = n_q;

  dim3 gAC(nbxMax, 4);
  dim3 gB(NB, 4);
  k_bcount<<<gAC, 256, 0, stream>>>(ei_s + Es, Es, ei_p + Ep, Ep,
                                    ei_rv + Erv, Erv, ei_rc + Erc, Erc,
                                    shF, shF, shH, shH, Mbuf);
  k_bscanA<<<gB, 256, 0, stream>>>(n_s, n_p, n_r, n_q, Mbuf, Tbuf);
  k_bscanB<<<4, 256, 0, stream>>>(Tbuf, Bbuf);
  k_bappend<<<gAC, 256, 0, stream>>>(ei_s, ei_s + Es, Es, ei_p, ei_p + Ep, Ep,
                                     ei_rv, ei_rv + Erv, Erv, ei_rc, ei_rc + Erc, Erc,
                                     shF, shF, shH, shH, Mbuf, Bbuf,
                                     scr_s, scr_p, scr_r, scr_q);
  k_doff<<<gB, 256, 0, stream>>>(scr_s, scr_p, scr_r, scr_q,
                                 shF, shF, shH, shH, NF, NF, NH, NH,
                                 Bbuf, off_s, off_p, off_r, off_q);
  k_place<<<gB, 256, 0, stream>>>(scr_s, scr_p, scr_r, scr_q,
                                  shF, shF, shH, shH, NF, NF, NH, NH,
                                  Bbuf, off_s, off_p, off_r, off_q,
                                  csr_s, csr_p, csr_r, csr_q);

  int gF = (NF + 31) / 32;   // 6250
  int gH = (NH + 31) / 32;   // 1563

  for (int blk = 0; blk < 2; ++blk){
    const u16* fcur = blk ? f16_0 : xf16;
    const u16* hcur = blk ? h16_0 : xh16;
    const float* scF = blk ? ssbuf + 0   : nullptr;
    const float* shFp = blk ? ssbuf + 128 : nullptr;
    const float* scH = blk ? ssbuf + 256 : nullptr;
    const float* shHp = blk ? ssbuf + 384 : nullptr;
    float* st = stats + blk * 512;

    GemmArgs F;
    F.M = NF;
    F.off0 = off_s; F.csr0 = csr_s; F.tab0 = hcur; F.sc0 = scH; F.sh0 = shHp;
    F.off1 = off_p; F.csr1 = csr_p; F.tab1 = fcur; F.sc1 = scF; F.sh1 = shFp;
    F.tabd = fcur; F.scd = scF; F.shd = shFp;
    F.Wt = wcat + (size_t)(blk*2 + 0) * 49152;
    F.bias = bcat + (blk*2 + 0) * 128;
    F.out32 = blk ? out_f : nullptr;
    F.out16 = blk ? nullptr : f16_0;
    F.gsum = st + 0; F.gsq = st + 128;

    GemmArgs H;
    H.M = NH;
    H.off0 = off_r; H.csr0 = csr_r; H.tab0 = fcur; H.sc0 = scF; H.sh0 = shFp;
    H.off1 = off_q; H.csr1 = csr_q; H.tab1 = fcur; H.sc1 = scF; H.sh1 = shFp;
    H.tabd = hcur; H.scd = scH; H.shd = shHp;
    H.Wt = wcat + (size_t)(blk*2 + 1) * 49152;
    H.bias = bcat + (blk*2 + 1) * 128;
    H.out32 = blk ? out_h : nullptr;
    H.out16 = blk ? nullptr : h16_0;
    H.gsum = st + 256; H.gsq = st + 384;

    k_gemm2<<<gH + gF, 256, 0, stream>>>(H, F, gH);

    float* ss = ssbuf + blk * 512;
    k_bn_finalize<<<1, 256, 0, stream>>>(st + 0, st + 128, 1.f/(float)NF,
                                         st + 256, st + 384, 1.f/(float)NH,
                                         gamma + blk*128, beta + blk*128,
                                         ss + 0, ss + 128, ss + 256, ss + 384);
  }

  k_apply2<<<2048, 256, 0, stream>>>(out_f, NF * FH / 4, ssbuf + 512 + 0,   ssbuf + 512 + 128,
                                     out_h, NH * FH / 4, ssbuf + 512 + 256, ssbuf + 512 + 384);
}